// Round 15
// baseline (382.948 us; speedup 1.0000x reference)
//
#include <hip/hip_runtime.h>
#include <hip/hip_bf16.h>

#define NUM_NODES 50000
#define NUM_EDGES 800000
#define NUM_HEADS 8
#define HEAD_DIM 32
#define SCAN_BLOCKS 49
#define NCHUNK32 1563   // ceil(50000/32)

typedef unsigned short ushort8 __attribute__((ext_vector_type(8)));
typedef float f32x4 __attribute__((ext_vector_type(4)));
typedef __bf16 bf16x8 __attribute__((ext_vector_type(8)));
typedef _Float16 h2 __attribute__((ext_vector_type(2)));

union BF8 { ushort8 u; bf16x8 b; };
union H8 { ushort8 u; h2 h[4]; };

#if defined(__has_builtin)
#if __has_builtin(__builtin_amdgcn_fdot2)
#define FDOT2(a, b, c) __builtin_amdgcn_fdot2((a), (b), (c), false)
#endif
#endif
#ifndef FDOT2
#define FDOT2(a, b, c) ((float)(a)[0] * (float)(b)[0] + (float)(a)[1] * (float)(b)[1] + (c))
#endif

__device__ __forceinline__ unsigned float_to_key(float f) {
    int i = __float_as_int(f);
    return (i >= 0) ? ((unsigned)i | 0x80000000u) : ~(unsigned)i;
}
__device__ __forceinline__ float key_to_float(unsigned u) {
    unsigned b = (u & 0x80000000u) ? (u & 0x7fffffffu) : ~u;
    return __int_as_float((int)b);
}
__device__ __forceinline__ float bf2f(unsigned short u) {
    return __uint_as_float(((unsigned)u) << 16);
}
__device__ __forceinline__ unsigned short f2bf(float f) {
    unsigned u = __float_as_uint(f);
    unsigned r = (u + 0x7fffu + ((u >> 16) & 1u)) >> 16;
    return (unsigned short)r;
}
__device__ __forceinline__ unsigned short f2h(float f) {
    _Float16 h = (_Float16)f;
    return *(unsigned short*)&h;
}
__device__ __forceinline__ float h2f(unsigned short u) {
    _Float16 h = *(const _Float16*)&u;
    return (float)h;
}

// ---------- CSR build ----------
__global__ __launch_bounds__(256) void deg_kernel(const int* __restrict__ dst_idx, int* __restrict__ deg) {
    int e = blockIdx.x * 256 + threadIdx.x;
    if (e < NUM_EDGES) atomicAdd(&deg[dst_idx[e]], 1);
}

__global__ __launch_bounds__(1024) void scanA_kernel(
    const int* __restrict__ deg, int* __restrict__ offs, int* __restrict__ blocksum)
{
    __shared__ int buf[1024];
    int tid = threadIdx.x;
    int i = blockIdx.x * 1024 + tid;
    int v = (i < NUM_NODES) ? deg[i] : 0;
    buf[tid] = v;
    __syncthreads();
    for (int off = 1; off < 1024; off <<= 1) {
        int t = (tid >= off) ? buf[tid - off] : 0;
        __syncthreads();
        buf[tid] += t;
        __syncthreads();
    }
    if (i < NUM_NODES) offs[i] = buf[tid] - v;
    if (tid == 1023) blocksum[blockIdx.x] = buf[1023];
}

__global__ __launch_bounds__(64) void scanB_kernel(
    const int* __restrict__ blocksum, int* __restrict__ carry, int* __restrict__ offs)
{
    if (threadIdx.x == 0) {
        int acc = 0;
        for (int b = 0; b < SCAN_BLOCKS; b++) { carry[b] = acc; acc += blocksum[b]; }
        offs[NUM_NODES] = acc;
    }
}

__global__ __launch_bounds__(256) void scanC_kernel(
    int* __restrict__ offs, const int* __restrict__ carry, int* __restrict__ cursor)
{
    int i = blockIdx.x * 256 + threadIdx.x;
    if (i < NUM_NODES) {
        int v = offs[i] + carry[i >> 10];
        offs[i] = v;
        cursor[i] = v;
    }
}

// scatter ONLY edge_of (4B)
__global__ __launch_bounds__(256) void fillA_kernel(
    const int* __restrict__ dst_idx, int* __restrict__ cursor, int* __restrict__ edge_of)
{
    int e = blockIdx.x * 256 + threadIdx.x;
    if (e < NUM_EDGES) {
        int pos = atomicAdd(&cursor[dst_idx[e]], 1);
        edge_of[pos] = e;
    }
}

// gather pass: coalesced edge_of, gather inputs, coalesced NT writes.
// sdp = s | (d<<16); twh[h][pos] = f16(t0*wt0[h] + t1*wt1[h] + bt[h])
__global__ __launch_bounds__(256) void fillB_kernel(
    const int* __restrict__ edge_of,
    const int* __restrict__ src_idx, const int* __restrict__ dst_idx,
    const float* __restrict__ edge_time, const float* __restrict__ node_time,
    const float* __restrict__ Wt, const float* __restrict__ bt,
    unsigned* __restrict__ sdp, unsigned short* __restrict__ twh)
{
    int pos = blockIdx.x * 256 + threadIdx.x;
    if (pos < NUM_EDGES) {
        int e = __builtin_nontemporal_load(&edge_of[pos]);
        int s = src_idx[e];
        int d = dst_idx[e];
        __builtin_nontemporal_store((unsigned)s | ((unsigned)d << 16), &sdp[pos]);
        float td = edge_time[e] - node_time[d];
        float t0 = (td > 0.f) ? 1.f : ((td < 0.f) ? -1.f : 0.f);
        float t1 = log1pf(fabsf(td) * (1.f / 3600.f));
#pragma unroll
        for (int h = 0; h < 8; h++) {
            float tw = t0 * Wt[h] + t1 * Wt[8 + h] + bt[h];
            __builtin_nontemporal_store(f2h(tw), &twh[(size_t)h * NUM_EDGES + pos]);
        }
    }
}

// ---------- weight transpose+cvt: Wt[1024 n][256 k] bf16 ----------
__global__ __launch_bounds__(256) void wtrans_kernel(
    const float* __restrict__ Wq, const float* __restrict__ Wk,
    const float* __restrict__ Wv, const float* __restrict__ Wo,
    unsigned short* __restrict__ Wt)
{
    __shared__ float t[64][65];
    int nb = blockIdx.x * 64;
    int kb = blockIdx.y * 64;
    int g = nb >> 8;
    const float* W = (g == 0) ? Wq : (g == 1) ? Wk : (g == 2) ? Wv : Wo;
    int n0 = nb & 255;
    int tx = threadIdx.x & 63;
    int ty = threadIdx.x >> 6;
#pragma unroll
    for (int i = 0; i < 16; i++) {
        int k = i * 4 + ty;
        t[tx][k] = W[(size_t)(kb + k) * 256 + n0 + tx];
    }
    __syncthreads();
#pragma unroll
    for (int i = 0; i < 16; i++) {
        int n = i * 4 + ty;
        Wt[(size_t)(nb + n) * 256 + kb + tx] = f2bf(t[n][tx]);
    }
}

// ---------- pack W into MFMA fragment order ----------
__global__ __launch_bounds__(256) void wpack_kernel(
    const unsigned short* __restrict__ Wt, unsigned short* __restrict__ Wpk)
{
    int gid = blockIdx.x * 256 + threadIdx.x;
    int lane = gid & 63;
    int fragidx = gid >> 6;
    int c2 = fragidx & 7;
    int nf = (fragidx >> 3) & 3;
    int cb = (fragidx >> 5) & 3;
    int g = fragidx >> 7;
    int l16 = lane & 15;
    int kg = lane >> 4;
    int n_col = g * 256 + cb * 64 + nf * 16 + l16;
    int k0 = c2 * 32 + kg * 8;
    ushort8 v = *(const ushort8*)(Wt + (size_t)n_col * 256 + k0);
    *(ushort8*)(Wpk + (size_t)gid * 8) = v;
}

// ---------- QKV GEMM via MFMA (q,k f16; v bf16; head-major) ----------
__global__ __launch_bounds__(256) void gemm_qkv_mfma7(
    const float* __restrict__ A, int M,
    const unsigned short* __restrict__ Wpk,
    const float* __restrict__ b0, const float* __restrict__ b1, const float* __restrict__ b2,
    unsigned short* __restrict__ O0, unsigned short* __restrict__ O1, unsigned short* __restrict__ O2)
{
    __shared__ unsigned short As[64 * 256];
    int tid = threadIdx.x;
    int rowbase = blockIdx.x * 64;

    {
        int rsub = tid >> 6;
        int c4 = (tid & 63) * 4;
        int cchunk = (tid & 63) >> 1;
        int sub = (tid & 1);
#pragma unroll
        for (int it = 0; it < 16; it++) {
            int row = it * 4 + rsub;
            int grow = rowbase + row;
            float4 av = make_float4(0.f, 0.f, 0.f, 0.f);
            if (grow < M) av = *(const float4*)(A + (size_t)grow * 256 + c4);
            ushort4 o;
            o.x = f2bf(av.x); o.y = f2bf(av.y); o.z = f2bf(av.z); o.w = f2bf(av.w);
            unsigned byte = row * 512 + ((unsigned)(cchunk ^ (row & 7)) << 4) + sub * 8;
            *(ushort4*)((char*)As + byte) = o;
        }
    }
    __syncthreads();

    int lane = tid & 63;
    int wid = tid >> 6;
    int l16 = lane & 15;
    int kg = lane >> 4;

#pragma unroll
    for (int p = 0; p < 3; p++) {
        const float* bias = (p == 0) ? b0 : (p == 1) ? b1 : b2;
        unsigned short* O = (p == 0) ? O0 : (p == 1) ? O1 : O2;

        f32x4 acc[4][4];
#pragma unroll
        for (int m = 0; m < 4; m++)
#pragma unroll
            for (int n = 0; n < 4; n++) acc[m][n] = (f32x4)(0.0f);

        const ushort8* wbase = (const ushort8*)(Wpk + ((size_t)(p * 4 + wid) * 2048 + lane) * 8);

#pragma unroll
        for (int c2 = 0; c2 < 8; c2++) {
            bf16x8 wfr[4];
#pragma unroll
            for (int n = 0; n < 4; n++) {
                BF8 t; t.u = wbase[(n * 8 + c2) * 64];
                wfr[n] = t.b;
            }
            bf16x8 afr[4];
#pragma unroll
            for (int m = 0; m < 4; m++) {
                int row = m * 16 + l16;
                int cchunk = (c2 * 4 + kg) ^ (row & 7);
                BF8 t;
                t.u = *(const ushort8*)((const char*)As + row * 512 + (cchunk << 4));
                afr[m] = t.b;
            }
#pragma unroll
            for (int m = 0; m < 4; m++)
#pragma unroll
                for (int n = 0; n < 4; n++)
                    acc[m][n] = __builtin_amdgcn_mfma_f32_16x16x32_bf16(wfr[n], afr[m], acc[m][n], 0, 0, 0);
        }

#pragma unroll
        for (int m = 0; m < 4; m++) {
            int node = rowbase + m * 16 + l16;
            if (node >= M) continue;
#pragma unroll
            for (int n = 0; n < 4; n++) {
                int lc = wid * 64 + n * 16 + kg * 4;
                float4 bv = *(const float4*)(bias + lc);
                ushort4 o;
                if (p < 2) {
                    o.x = f2h(acc[m][n][0] + bv.x);
                    o.y = f2h(acc[m][n][1] + bv.y);
                    o.z = f2h(acc[m][n][2] + bv.z);
                    o.w = f2h(acc[m][n][3] + bv.w);
                } else {
                    o.x = f2bf(acc[m][n][0] + bv.x);
                    o.y = f2bf(acc[m][n][1] + bv.y);
                    o.z = f2bf(acc[m][n][2] + bv.z);
                    o.w = f2bf(acc[m][n][3] + bv.w);
                }
                int hh = lc >> 5, dd = lc & 31;
                *(ushort4*)(O + ((size_t)hh * NUM_NODES + node) * 32 + dd) = o;
            }
        }
    }
}

// ---------- output GEMM, packed-W; per-head scale in staging ----------
__global__ __launch_bounds__(256) void gemm_out_mfma6(
    const unsigned short* __restrict__ aggb, int M,
    const unsigned short* __restrict__ Wpk,
    const float* __restrict__ bias, const float* __restrict__ kscale,
    float* __restrict__ C)
{
    __shared__ unsigned short As[64 * 256];
    int tid = threadIdx.x;
    int rowbase = blockIdx.x * 64;

    {
        int rsub = tid >> 6;
        int c4 = (tid & 63) * 4;
        int cchunk = (tid & 63) >> 1;
        int sub = (tid & 1);
        int hh = c4 >> 5, dd = c4 & 31;
        float ks = kscale[hh];
#pragma unroll
        for (int it = 0; it < 16; it++) {
            int row = it * 4 + rsub;
            int grow = rowbase + row;
            ushort4 av = make_ushort4(0, 0, 0, 0);
            if (grow < M) av = *(const ushort4*)(aggb + ((size_t)hh * NUM_NODES + grow) * 32 + dd);
            ushort4 o;
            o.x = f2bf(bf2f(av.x) * ks); o.y = f2bf(bf2f(av.y) * ks);
            o.z = f2bf(bf2f(av.z) * ks); o.w = f2bf(bf2f(av.w) * ks);
            unsigned byte = row * 512 + ((unsigned)(cchunk ^ (row & 7)) << 4) + sub * 8;
            *(ushort4*)((char*)As + byte) = o;
        }
    }
    __syncthreads();

    int lane = tid & 63;
    int wid = tid >> 6;
    int l16 = lane & 15;
    int kg = lane >> 4;

    f32x4 acc[4][4];
#pragma unroll
    for (int m = 0; m < 4; m++)
#pragma unroll
        for (int n = 0; n < 4; n++) acc[m][n] = (f32x4)(0.0f);

    const ushort8* wbase = (const ushort8*)(Wpk + ((size_t)wid * 2048 + lane) * 8);

#pragma unroll
    for (int c2 = 0; c2 < 8; c2++) {
        bf16x8 wfr[4];
#pragma unroll
        for (int n = 0; n < 4; n++) {
            BF8 t; t.u = wbase[(n * 8 + c2) * 64];
            wfr[n] = t.b;
        }
        bf16x8 afr[4];
#pragma unroll
        for (int m = 0; m < 4; m++) {
            int row = m * 16 + l16;
            int cchunk = (c2 * 4 + kg) ^ (row & 7);
            BF8 t;
            t.u = *(const ushort8*)((const char*)As + row * 512 + (cchunk << 4));
            afr[m] = t.b;
        }
#pragma unroll
        for (int m = 0; m < 4; m++)
#pragma unroll
            for (int n = 0; n < 4; n++)
                acc[m][n] = __builtin_amdgcn_mfma_f32_16x16x32_bf16(wfr[n], afr[m], acc[m][n], 0, 0, 0);
    }

#pragma unroll
    for (int m = 0; m < 4; m++) {
        int node = rowbase + m * 16 + l16;
        if (node >= M) continue;
#pragma unroll
        for (int n = 0; n < 4; n++) {
            int col = wid * 64 + n * 16 + kg * 4;
            float4 bv = *(const float4*)(bias + col);
            float4 o;
            o.x = acc[m][n][0] + bv.x;
            o.y = acc[m][n][1] + bv.y;
            o.z = acc[m][n][2] + bv.z;
            o.w = acc[m][n][3] + bv.w;
            *(float4*)(C + (size_t)node * 256 + col) = o;
        }
    }
}

// ---------- scores: f16 q/k, fdot2, NT streams, f16 score out; head-pinned ----------
__global__ __launch_bounds__(256) void score6_kernel(
    const unsigned short* __restrict__ qh, const unsigned short* __restrict__ kh,
    const unsigned* __restrict__ sdp, const unsigned short* __restrict__ twh,
    unsigned short* __restrict__ scores, unsigned* __restrict__ partialmax)
{
    __shared__ unsigned sm;
    int tid = threadIdx.x;
    if (tid == 0) sm = 0u;
    __syncthreads();
    int h = blockIdx.x & 7;
    int blk = blockIdx.x >> 3;               // 0..255
    const unsigned short* qhh = qh + (size_t)h * NUM_NODES * 32;
    const unsigned short* khh = kh + (size_t)h * NUM_NODES * 32;
    const unsigned short* tw_h = twh + (size_t)h * NUM_EDGES;
    unsigned short* sc_h = scores + (size_t)h * NUM_EDGES;
    unsigned mykey = 0u;
    const int stride = 256 * 256;
    for (int pos = blk * 256 + tid; pos < NUM_EDGES; pos += stride) {
        unsigned sdv = __builtin_nontemporal_load(&sdp[pos]);
        int s = sdv & 0xffffu;
        int d = sdv >> 16;
        float tw = h2f(__builtin_nontemporal_load(&tw_h[pos]));
        const ushort8* qp = (const ushort8*)(qhh + (size_t)d * 32);
        const ushort8* kp = (const ushort8*)(khh + (size_t)s * 32);
        float dotv = 0.f;
#pragma unroll
        for (int i = 0; i < 4; i++) {
            H8 a, b;
            a.u = qp[i]; b.u = kp[i];
#pragma unroll
            for (int j = 0; j < 4; j++) dotv = FDOT2(a.h[j], b.h[j], dotv);
        }
        float sc = dotv * 0.17677669529663687f + tw;
        __builtin_nontemporal_store(f2h(sc), &sc_h[pos]);
        unsigned kkey = float_to_key(sc);
        mykey = (kkey > mykey) ? kkey : mykey;
    }
#pragma unroll
    for (int off = 32; off > 0; off >>= 1) {
        unsigned o = __shfl_xor(mykey, off, 64);
        mykey = (o > mykey) ? o : mykey;
    }
    if ((tid & 63) == 0) atomicMax(&sm, mykey);
    __syncthreads();
    if (tid == 0) partialmax[blockIdx.x] = sm;
}

// partialmax[2048], entry i belongs to head i&7 (256 per head)
__global__ __launch_bounds__(256) void reduce_max3_kernel(
    const unsigned* __restrict__ partialmax, float* __restrict__ headmax)
{
    int tid = threadIdx.x;
    int h = tid >> 5, lane = tid & 31;
    unsigned m = 0u;
    for (int i = lane; i < 256; i += 32) {
        unsigned v = partialmax[i * 8 + h];
        m = (v > m) ? v : m;
    }
    for (int off = 16; off > 0; off >>= 1) {
        unsigned o = __shfl_down(m, off, 32);
        m = (o > m) ? o : m;
    }
    if (lane == 0) headmax[h] = key_to_float(m);
}

// ---------- aggregate: head-pinned, LDS-staged (NT streams), psum partials ----------
__global__ __launch_bounds__(256) void aggregate9_kernel(
    const unsigned short* __restrict__ vh, const unsigned short* __restrict__ scores,
    const unsigned* __restrict__ sdp, const int* __restrict__ offs,
    const float* __restrict__ headmax, unsigned short* __restrict__ aggb,
    float* __restrict__ psum_part)
{
    __shared__ int sSrc[512];
    __shared__ float sP[512];
    __shared__ float blocksum;
    int tid = threadIdx.x;
    int h = blockIdx.x & 7;
    int chunk = blockIdx.x >> 3;
    int nodebase = chunk * 32;
    int g = tid >> 3;
    int ln = tid & 7;
    int node = nodebase + g;
    float m = headmax[h];
    const unsigned short* sc_h = scores + (size_t)h * NUM_EDGES;
    const unsigned short* vhh = vh + (size_t)h * NUM_NODES * 32;
    if (tid == 0) blocksum = 0.f;

    int blkstart = offs[nodebase];
    int blkend = offs[(nodebase + 32 < NUM_NODES) ? (nodebase + 32) : NUM_NODES];
    int start = 0, end = 0;
    if (node < NUM_NODES) { start = offs[node]; end = offs[node + 1]; }

    f32x4 a0 = (f32x4)(0.f), a1 = (f32x4)(0.f);
    float ps = 0.f;

    for (int t0 = blkstart; t0 < blkend; t0 += 512) {
        int cnt = min(512, blkend - t0);
        __syncthreads();
        for (int i = tid; i < cnt; i += 256) {
            sSrc[i] = (int)(__builtin_nontemporal_load(&sdp[t0 + i]) & 0xffffu);
            float p = __expf(h2f(__builtin_nontemporal_load(&sc_h[t0 + i])) - m);
            sP[i] = p;
            ps += p;
        }
        __syncthreads();
        int lo = (start > t0) ? start : t0;
        int hi = (end < t0 + cnt) ? end : (t0 + cnt);
        int cb = lo;
        for (; cb + 2 <= hi; cb += 2) {
            int i0 = cb - t0;
            int s0 = sSrc[i0], s1 = sSrc[i0 + 1];
            float p0 = sP[i0], p1 = sP[i0 + 1];
            ushort4 v0 = *(const ushort4*)(vhh + (size_t)s0 * 32 + ln * 4);
            ushort4 v1 = *(const ushort4*)(vhh + (size_t)s1 * 32 + ln * 4);
            a0[0] += p0 * bf2f(v0.x); a0[1] += p0 * bf2f(v0.y);
            a0[2] += p0 * bf2f(v0.z); a0[3] += p0 * bf2f(v0.w);
            a1[0] += p1 * bf2f(v1.x); a1[1] += p1 * bf2f(v1.y);
            a1[2] += p1 * bf2f(v1.z); a1[3] += p1 * bf2f(v1.w);
        }
        if (cb < hi) {
            int i0 = cb - t0;
            int s0 = sSrc[i0];
            float p0 = sP[i0];
            ushort4 v0 = *(const ushort4*)(vhh + (size_t)s0 * 32 + ln * 4);
            a0[0] += p0 * bf2f(v0.x); a0[1] += p0 * bf2f(v0.y);
            a0[2] += p0 * bf2f(v0.z); a0[3] += p0 * bf2f(v0.w);
        }
    }

    if (node < NUM_NODES) {
        ushort4 o;
        o.x = f2bf(a0[0] + a1[0]); o.y = f2bf(a0[1] + a1[1]);
        o.z = f2bf(a0[2] + a1[2]); o.w = f2bf(a0[3] + a1[3]);
        *(ushort4*)(aggb + ((size_t)h * NUM_NODES + node) * 32 + ln * 4) = o;
    }

    __syncthreads();
#pragma unroll
    for (int off = 32; off > 0; off >>= 1) ps += __shfl_xor(ps, off, 64);
    if ((tid & 63) == 0) atomicAdd(&blocksum, ps);
    __syncthreads();
    if (tid == 0) psum_part[blockIdx.x] = blocksum;
}

__global__ __launch_bounds__(256) void reduce_psum2_kernel(
    const float* __restrict__ psum_part, float* __restrict__ headinv)
{
    int tid = threadIdx.x;
    int h = tid >> 5, lane = tid & 31;
    float s = 0.f;
    for (int i = lane; i < NCHUNK32; i += 32) s += psum_part[i * 8 + h];
    for (int off = 16; off > 0; off >>= 1) s += __shfl_down(s, off, 32);
    if (lane == 0) headinv[h] = 1.f / s;
}

extern "C" void kernel_launch(void* const* d_in, const int* in_sizes, int n_in,
                              void* d_out, int out_size, void* d_ws, size_t ws_size,
                              hipStream_t stream) {
    const float* x = (const float*)d_in[0];
    const int* ei = (const int*)d_in[1];
    const int* src_idx = ei;
    const int* dst_idx = ei + NUM_EDGES;
    const float* edge_time = (const float*)d_in[2];
    const float* node_time = (const float*)d_in[3];
    const float* Wq = (const float*)d_in[4];  const float* bq = (const float*)d_in[5];
    const float* Wk = (const float*)d_in[6];  const float* bk = (const float*)d_in[7];
    const float* Wv = (const float*)d_in[8];  const float* bv = (const float*)d_in[9];
    const float* Wt = (const float*)d_in[10]; const float* bt = (const float*)d_in[11];
    const float* Wo = (const float*)d_in[12]; const float* bo = (const float*)d_in[13];
    float* out = (float*)d_out;

    char* w = (char*)d_ws;
    unsigned short* qb = (unsigned short*)w; w += (size_t)NUM_NODES * 256 * 2;  // [8][N][32] f16
    unsigned short* kb = (unsigned short*)w; w += (size_t)NUM_NODES * 256 * 2;  // [8][N][32] f16
    unsigned short* vb = (unsigned short*)w; w += (size_t)NUM_NODES * 256 * 2;  // [8][N][32] bf16
    unsigned short* scores = (unsigned short*)w; w += (size_t)NUM_EDGES * 8 * 2; // [8][E] f16
    unsigned short* twh = (unsigned short*)w; w += (size_t)NUM_EDGES * 8 * 2;   // [8][E] f16
    unsigned short* aggb = (unsigned short*)w; w += (size_t)NUM_NODES * 256 * 2; // [8][N][32]
    unsigned* sdp = (unsigned*)w;   w += (size_t)NUM_EDGES * 4;
    int* edge_of = (int*)w;         w += (size_t)NUM_EDGES * 4;
    int* deg = (int*)w;             w += (size_t)NUM_NODES * 4;
    int* offs = (int*)w;            w += (size_t)(NUM_NODES + 1) * 4;
    int* cursor = (int*)w;          w += (size_t)NUM_NODES * 4;
    unsigned* partialmax = (unsigned*)w; w += 2048 * 4;
    float* psum_part = (float*)w;   w += (size_t)NCHUNK32 * 8 * 4;
    float* headmax = (float*)w;     w += 8 * 4;
    float* headinv = (float*)w;     w += 8 * 4;
    int* blocksum = (int*)w;        w += 64 * 4;
    int* bcarry = (int*)w;          w += 64 * 4;
    unsigned short* Wtb = (unsigned short*)w; w += (size_t)1024 * 256 * 2;
    unsigned short* Wpk = (unsigned short*)w; w += (size_t)1024 * 256 * 2;

    hipMemsetAsync(deg, 0, (size_t)NUM_NODES * 4, stream);

    // weight transpose + bf16 cvt, then fragment-pack
    dim3 gw(16, 4);
    wtrans_kernel<<<gw, 256, 0, stream>>>(Wq, Wk, Wv, Wo, Wtb);
    wpack_kernel<<<128, 256, 0, stream>>>(Wtb, Wpk);

    // CSR by dst (parallel scan); minimal scatter then gather-fill
    deg_kernel<<<(NUM_EDGES + 255) / 256, 256, 0, stream>>>(dst_idx, deg);
    scanA_kernel<<<SCAN_BLOCKS, 1024, 0, stream>>>(deg, offs, blocksum);
    scanB_kernel<<<1, 64, 0, stream>>>(blocksum, bcarry, offs);
    scanC_kernel<<<(NUM_NODES + 255) / 256, 256, 0, stream>>>(offs, bcarry, cursor);
    fillA_kernel<<<(NUM_EDGES + 255) / 256, 256, 0, stream>>>(dst_idx, cursor, edge_of);
    fillB_kernel<<<(NUM_EDGES + 255) / 256, 256, 0, stream>>>(
        edge_of, src_idx, dst_idx, edge_time, node_time, Wt, bt, sdp, twh);

    // QKV projection -> head-major q/k (f16) + v (bf16)
    gemm_qkv_mfma7<<<(NUM_NODES + 63) / 64, 256, 0, stream>>>(
        x, NUM_NODES, Wpk, bq, bk, bv, qb, kb, vb);

    // scores (head-pinned, fdot2, NT streams) + per-head max
    score6_kernel<<<2048, 256, 0, stream>>>(qb, kb, sdp, twh, scores, partialmax);
    reduce_max3_kernel<<<1, 256, 0, stream>>>(partialmax, headmax);

    // aggregate (head-pinned, NT-staged src+p, inline exp) + psum partials
    aggregate9_kernel<<<NCHUNK32 * 8, 256, 0, stream>>>(
        vb, scores, sdp, offs, headmax, aggb, psum_part);
    reduce_psum2_kernel<<<1, 256, 0, stream>>>(psum_part, headinv);

    // output projection with per-head 1/sum folded into staging (packed-W)
    gemm_out_mfma6<<<(NUM_NODES + 63) / 64, 256, 0, stream>>>(
        aggb, NUM_NODES, Wpk + (size_t)768 * 256, bo, headinv, out);
}

// Round 16
// 382.111 us; speedup vs baseline: 1.0022x; 1.0022x over previous
//
#include <hip/hip_runtime.h>
#include <hip/hip_bf16.h>

#define NUM_NODES 50000
#define NUM_EDGES 800000
#define NUM_HEADS 8
#define HEAD_DIM 32
#define SCAN_BLOCKS 49
#define NCHUNK32 1563   // ceil(50000/32)

typedef unsigned short ushort8 __attribute__((ext_vector_type(8)));
typedef float f32x4 __attribute__((ext_vector_type(4)));
typedef __bf16 bf16x8 __attribute__((ext_vector_type(8)));
typedef _Float16 h2 __attribute__((ext_vector_type(2)));

union BF8 { ushort8 u; bf16x8 b; };
union H8 { ushort8 u; h2 h[4]; };

#if defined(__has_builtin)
#if __has_builtin(__builtin_amdgcn_fdot2)
#define FDOT2(a, b, c) __builtin_amdgcn_fdot2((a), (b), (c), false)
#endif
#endif
#ifndef FDOT2
#define FDOT2(a, b, c) ((float)(a)[0] * (float)(b)[0] + (float)(a)[1] * (float)(b)[1] + (c))
#endif

__device__ __forceinline__ unsigned float_to_key(float f) {
    int i = __float_as_int(f);
    return (i >= 0) ? ((unsigned)i | 0x80000000u) : ~(unsigned)i;
}
__device__ __forceinline__ float key_to_float(unsigned u) {
    unsigned b = (u & 0x80000000u) ? (u & 0x7fffffffu) : ~u;
    return __int_as_float((int)b);
}
__device__ __forceinline__ float bf2f(unsigned short u) {
    return __uint_as_float(((unsigned)u) << 16);
}
__device__ __forceinline__ unsigned short f2bf(float f) {
    unsigned u = __float_as_uint(f);
    unsigned r = (u + 0x7fffu + ((u >> 16) & 1u)) >> 16;
    return (unsigned short)r;
}
__device__ __forceinline__ unsigned short f2h(float f) {
    _Float16 h = (_Float16)f;
    return *(unsigned short*)&h;
}
__device__ __forceinline__ float h2f(unsigned short u) {
    _Float16 h = *(const _Float16*)&u;
    return (float)h;
}

// ---------- CSR build ----------
__global__ __launch_bounds__(256) void deg_kernel(const int* __restrict__ dst_idx, int* __restrict__ deg) {
    int e = blockIdx.x * 256 + threadIdx.x;
    if (e < NUM_EDGES) atomicAdd(&deg[dst_idx[e]], 1);
}

__global__ __launch_bounds__(1024) void scanA_kernel(
    const int* __restrict__ deg, int* __restrict__ offs, int* __restrict__ blocksum)
{
    __shared__ int buf[1024];
    int tid = threadIdx.x;
    int i = blockIdx.x * 1024 + tid;
    int v = (i < NUM_NODES) ? deg[i] : 0;
    buf[tid] = v;
    __syncthreads();
    for (int off = 1; off < 1024; off <<= 1) {
        int t = (tid >= off) ? buf[tid - off] : 0;
        __syncthreads();
        buf[tid] += t;
        __syncthreads();
    }
    if (i < NUM_NODES) offs[i] = buf[tid] - v;
    if (tid == 1023) blocksum[blockIdx.x] = buf[1023];
}

__global__ __launch_bounds__(64) void scanB_kernel(
    const int* __restrict__ blocksum, int* __restrict__ carry, int* __restrict__ offs)
{
    if (threadIdx.x == 0) {
        int acc = 0;
        for (int b = 0; b < SCAN_BLOCKS; b++) { carry[b] = acc; acc += blocksum[b]; }
        offs[NUM_NODES] = acc;
    }
}

__global__ __launch_bounds__(256) void scanC_kernel(
    int* __restrict__ offs, const int* __restrict__ carry, int* __restrict__ cursor)
{
    int i = blockIdx.x * 256 + threadIdx.x;
    if (i < NUM_NODES) {
        int v = offs[i] + carry[i >> 10];
        offs[i] = v;
        cursor[i] = v;
    }
}

// scatter ONLY edge_of (4B)
__global__ __launch_bounds__(256) void fillA_kernel(
    const int* __restrict__ dst_idx, int* __restrict__ cursor, int* __restrict__ edge_of)
{
    int e = blockIdx.x * 256 + threadIdx.x;
    if (e < NUM_EDGES) {
        int pos = atomicAdd(&cursor[dst_idx[e]], 1);
        edge_of[pos] = e;
    }
}

// gather pass: coalesced edge_of, gather inputs (L2-resident), coalesced NT writes.
// sdp = s | (d<<16); tfh = f16(t0) | (f16(t1)<<16)
__global__ __launch_bounds__(256) void fillB_kernel(
    const int* __restrict__ edge_of,
    const int* __restrict__ src_idx, const int* __restrict__ dst_idx,
    const float* __restrict__ edge_time, const float* __restrict__ node_time,
    unsigned* __restrict__ sdp, unsigned* __restrict__ tfh)
{
    int pos = blockIdx.x * 256 + threadIdx.x;
    if (pos < NUM_EDGES) {
        int e = __builtin_nontemporal_load(&edge_of[pos]);
        int s = src_idx[e];
        int d = dst_idx[e];
        __builtin_nontemporal_store((unsigned)s | ((unsigned)d << 16), &sdp[pos]);
        float td = edge_time[e] - node_time[d];
        float t0 = (td > 0.f) ? 1.f : ((td < 0.f) ? -1.f : 0.f);
        float t1 = log1pf(fabsf(td) * (1.f / 3600.f));
        __builtin_nontemporal_store((unsigned)f2h(t0) | ((unsigned)f2h(t1) << 16), &tfh[pos]);
    }
}

// ---------- weight transpose+cvt: Wt[1024 n][256 k] bf16 ----------
__global__ __launch_bounds__(256) void wtrans_kernel(
    const float* __restrict__ Wq, const float* __restrict__ Wk,
    const float* __restrict__ Wv, const float* __restrict__ Wo,
    unsigned short* __restrict__ Wt)
{
    __shared__ float t[64][65];
    int nb = blockIdx.x * 64;
    int kb = blockIdx.y * 64;
    int g = nb >> 8;
    const float* W = (g == 0) ? Wq : (g == 1) ? Wk : (g == 2) ? Wv : Wo;
    int n0 = nb & 255;
    int tx = threadIdx.x & 63;
    int ty = threadIdx.x >> 6;
#pragma unroll
    for (int i = 0; i < 16; i++) {
        int k = i * 4 + ty;
        t[tx][k] = W[(size_t)(kb + k) * 256 + n0 + tx];
    }
    __syncthreads();
#pragma unroll
    for (int i = 0; i < 16; i++) {
        int n = i * 4 + ty;
        Wt[(size_t)(nb + n) * 256 + kb + tx] = f2bf(t[n][tx]);
    }
}

// ---------- pack W into MFMA fragment order ----------
__global__ __launch_bounds__(256) void wpack_kernel(
    const unsigned short* __restrict__ Wt, unsigned short* __restrict__ Wpk)
{
    int gid = blockIdx.x * 256 + threadIdx.x;
    int lane = gid & 63;
    int fragidx = gid >> 6;
    int c2 = fragidx & 7;
    int nf = (fragidx >> 3) & 3;
    int cb = (fragidx >> 5) & 3;
    int g = fragidx >> 7;
    int l16 = lane & 15;
    int kg = lane >> 4;
    int n_col = g * 256 + cb * 64 + nf * 16 + l16;
    int k0 = c2 * 32 + kg * 8;
    ushort8 v = *(const ushort8*)(Wt + (size_t)n_col * 256 + k0);
    *(ushort8*)(Wpk + (size_t)gid * 8) = v;
}

// ---------- QKV GEMM via MFMA (q,k f16; v bf16; head-major) ----------
__global__ __launch_bounds__(256) void gemm_qkv_mfma7(
    const float* __restrict__ A, int M,
    const unsigned short* __restrict__ Wpk,
    const float* __restrict__ b0, const float* __restrict__ b1, const float* __restrict__ b2,
    unsigned short* __restrict__ O0, unsigned short* __restrict__ O1, unsigned short* __restrict__ O2)
{
    __shared__ unsigned short As[64 * 256];
    int tid = threadIdx.x;
    int rowbase = blockIdx.x * 64;

    {
        int rsub = tid >> 6;
        int c4 = (tid & 63) * 4;
        int cchunk = (tid & 63) >> 1;
        int sub = (tid & 1);
#pragma unroll
        for (int it = 0; it < 16; it++) {
            int row = it * 4 + rsub;
            int grow = rowbase + row;
            float4 av = make_float4(0.f, 0.f, 0.f, 0.f);
            if (grow < M) av = *(const float4*)(A + (size_t)grow * 256 + c4);
            ushort4 o;
            o.x = f2bf(av.x); o.y = f2bf(av.y); o.z = f2bf(av.z); o.w = f2bf(av.w);
            unsigned byte = row * 512 + ((unsigned)(cchunk ^ (row & 7)) << 4) + sub * 8;
            *(ushort4*)((char*)As + byte) = o;
        }
    }
    __syncthreads();

    int lane = tid & 63;
    int wid = tid >> 6;
    int l16 = lane & 15;
    int kg = lane >> 4;

#pragma unroll
    for (int p = 0; p < 3; p++) {
        const float* bias = (p == 0) ? b0 : (p == 1) ? b1 : b2;
        unsigned short* O = (p == 0) ? O0 : (p == 1) ? O1 : O2;

        f32x4 acc[4][4];
#pragma unroll
        for (int m = 0; m < 4; m++)
#pragma unroll
            for (int n = 0; n < 4; n++) acc[m][n] = (f32x4)(0.0f);

        const ushort8* wbase = (const ushort8*)(Wpk + ((size_t)(p * 4 + wid) * 2048 + lane) * 8);

#pragma unroll
        for (int c2 = 0; c2 < 8; c2++) {
            bf16x8 wfr[4];
#pragma unroll
            for (int n = 0; n < 4; n++) {
                BF8 t; t.u = wbase[(n * 8 + c2) * 64];
                wfr[n] = t.b;
            }
            bf16x8 afr[4];
#pragma unroll
            for (int m = 0; m < 4; m++) {
                int row = m * 16 + l16;
                int cchunk = (c2 * 4 + kg) ^ (row & 7);
                BF8 t;
                t.u = *(const ushort8*)((const char*)As + row * 512 + (cchunk << 4));
                afr[m] = t.b;
            }
#pragma unroll
            for (int m = 0; m < 4; m++)
#pragma unroll
                for (int n = 0; n < 4; n++)
                    acc[m][n] = __builtin_amdgcn_mfma_f32_16x16x32_bf16(wfr[n], afr[m], acc[m][n], 0, 0, 0);
        }

#pragma unroll
        for (int m = 0; m < 4; m++) {
            int node = rowbase + m * 16 + l16;
            if (node >= M) continue;
#pragma unroll
            for (int n = 0; n < 4; n++) {
                int lc = wid * 64 + n * 16 + kg * 4;
                float4 bv = *(const float4*)(bias + lc);
                ushort4 o;
                if (p < 2) {
                    o.x = f2h(acc[m][n][0] + bv.x);
                    o.y = f2h(acc[m][n][1] + bv.y);
                    o.z = f2h(acc[m][n][2] + bv.z);
                    o.w = f2h(acc[m][n][3] + bv.w);
                } else {
                    o.x = f2bf(acc[m][n][0] + bv.x);
                    o.y = f2bf(acc[m][n][1] + bv.y);
                    o.z = f2bf(acc[m][n][2] + bv.z);
                    o.w = f2bf(acc[m][n][3] + bv.w);
                }
                int hh = lc >> 5, dd = lc & 31;
                *(ushort4*)(O + ((size_t)hh * NUM_NODES + node) * 32 + dd) = o;
            }
        }
    }
}

// ---------- output GEMM, packed-W; per-head scale in staging ----------
__global__ __launch_bounds__(256) void gemm_out_mfma6(
    const unsigned short* __restrict__ aggb, int M,
    const unsigned short* __restrict__ Wpk,
    const float* __restrict__ bias, const float* __restrict__ kscale,
    float* __restrict__ C)
{
    __shared__ unsigned short As[64 * 256];
    int tid = threadIdx.x;
    int rowbase = blockIdx.x * 64;

    {
        int rsub = tid >> 6;
        int c4 = (tid & 63) * 4;
        int cchunk = (tid & 63) >> 1;
        int sub = (tid & 1);
        int hh = c4 >> 5, dd = c4 & 31;
        float ks = kscale[hh];
#pragma unroll
        for (int it = 0; it < 16; it++) {
            int row = it * 4 + rsub;
            int grow = rowbase + row;
            ushort4 av = make_ushort4(0, 0, 0, 0);
            if (grow < M) av = *(const ushort4*)(aggb + ((size_t)hh * NUM_NODES + grow) * 32 + dd);
            ushort4 o;
            o.x = f2bf(bf2f(av.x) * ks); o.y = f2bf(bf2f(av.y) * ks);
            o.z = f2bf(bf2f(av.z) * ks); o.w = f2bf(bf2f(av.w) * ks);
            unsigned byte = row * 512 + ((unsigned)(cchunk ^ (row & 7)) << 4) + sub * 8;
            *(ushort4*)((char*)As + byte) = o;
        }
    }
    __syncthreads();

    int lane = tid & 63;
    int wid = tid >> 6;
    int l16 = lane & 15;
    int kg = lane >> 4;

    f32x4 acc[4][4];
#pragma unroll
    for (int m = 0; m < 4; m++)
#pragma unroll
        for (int n = 0; n < 4; n++) acc[m][n] = (f32x4)(0.0f);

    const ushort8* wbase = (const ushort8*)(Wpk + ((size_t)wid * 2048 + lane) * 8);

#pragma unroll
    for (int c2 = 0; c2 < 8; c2++) {
        bf16x8 wfr[4];
#pragma unroll
        for (int n = 0; n < 4; n++) {
            BF8 t; t.u = wbase[(n * 8 + c2) * 64];
            wfr[n] = t.b;
        }
        bf16x8 afr[4];
#pragma unroll
        for (int m = 0; m < 4; m++) {
            int row = m * 16 + l16;
            int cchunk = (c2 * 4 + kg) ^ (row & 7);
            BF8 t;
            t.u = *(const ushort8*)((const char*)As + row * 512 + (cchunk << 4));
            afr[m] = t.b;
        }
#pragma unroll
        for (int m = 0; m < 4; m++)
#pragma unroll
            for (int n = 0; n < 4; n++)
                acc[m][n] = __builtin_amdgcn_mfma_f32_16x16x32_bf16(wfr[n], afr[m], acc[m][n], 0, 0, 0);
    }

#pragma unroll
    for (int m = 0; m < 4; m++) {
        int node = rowbase + m * 16 + l16;
        if (node >= M) continue;
#pragma unroll
        for (int n = 0; n < 4; n++) {
            int col = wid * 64 + n * 16 + kg * 4;
            float4 bv = *(const float4*)(bias + col);
            float4 o;
            o.x = acc[m][n][0] + bv.x;
            o.y = acc[m][n][1] + bv.y;
            o.z = acc[m][n][2] + bv.z;
            o.w = acc[m][n][3] + bv.w;
            *(float4*)(C + (size_t)node * 256 + col) = o;
        }
    }
}

// ---------- scores: lane-quad per edge; f16 q/k fdot2; head-pinned ----------
__global__ __launch_bounds__(256) void score7_kernel(
    const unsigned short* __restrict__ qh, const unsigned short* __restrict__ kh,
    const unsigned* __restrict__ sdp, const unsigned* __restrict__ tfh,
    const float* __restrict__ Wt, const float* __restrict__ bt,
    unsigned short* __restrict__ scores, unsigned* __restrict__ partialmax)
{
    __shared__ unsigned sm;
    int tid = threadIdx.x;
    if (tid == 0) sm = 0u;
    __syncthreads();
    int h = blockIdx.x & 7;
    int blk = blockIdx.x >> 3;               // 0..255
    float wt0 = Wt[h], wt1 = Wt[8 + h], btv = bt[h];
    const unsigned short* qhh = qh + (size_t)h * NUM_NODES * 32;
    const unsigned short* khh = kh + (size_t)h * NUM_NODES * 32;
    unsigned short* sc_h = scores + (size_t)h * NUM_EDGES;
    int quad = tid >> 2;       // 0..63
    int lq = tid & 3;          // 16B slot within 64B row
    unsigned mykey = 0u;
    const int qstride = 256 * 64;    // quads per head
    for (int pos = blk * 64 + quad; pos < NUM_EDGES; pos += qstride) {
        unsigned sdv = __builtin_nontemporal_load(&sdp[pos]);
        unsigned tp = __builtin_nontemporal_load(&tfh[pos]);
        int s = sdv & 0xffffu;
        int d = sdv >> 16;
        H8 a, b;
        a.u = *(const ushort8*)(qhh + (size_t)d * 32 + lq * 8);
        b.u = *(const ushort8*)(khh + (size_t)s * 32 + lq * 8);
        float dotv = 0.f;
#pragma unroll
        for (int j = 0; j < 4; j++) dotv = FDOT2(a.h[j], b.h[j], dotv);
        dotv += __shfl_xor(dotv, 1, 64);
        dotv += __shfl_xor(dotv, 2, 64);
        float t0 = h2f((unsigned short)(tp & 0xffffu));
        float t1 = h2f((unsigned short)(tp >> 16));
        float sc = dotv * 0.17677669529663687f + (t0 * wt0 + t1 * wt1 + btv);
        if (lq == 0) __builtin_nontemporal_store(f2h(sc), &sc_h[pos]);
        unsigned kkey = float_to_key(sc);
        mykey = (kkey > mykey) ? kkey : mykey;
    }
#pragma unroll
    for (int off = 32; off > 0; off >>= 1) {
        unsigned o = __shfl_xor(mykey, off, 64);
        mykey = (o > mykey) ? o : mykey;
    }
    if ((tid & 63) == 0) atomicMax(&sm, mykey);
    __syncthreads();
    if (tid == 0) partialmax[blockIdx.x] = sm;
}

// partialmax[2048], entry i belongs to head i&7 (256 per head)
__global__ __launch_bounds__(256) void reduce_max3_kernel(
    const unsigned* __restrict__ partialmax, float* __restrict__ headmax)
{
    int tid = threadIdx.x;
    int h = tid >> 5, lane = tid & 31;
    unsigned m = 0u;
    for (int i = lane; i < 256; i += 32) {
        unsigned v = partialmax[i * 8 + h];
        m = (v > m) ? v : m;
    }
    for (int off = 16; off > 0; off >>= 1) {
        unsigned o = __shfl_down(m, off, 32);
        m = (o > m) ? o : m;
    }
    if (lane == 0) headmax[h] = key_to_float(m);
}

// ---------- aggregate: head-pinned, LDS-staged src+p (regular loads), psum ----------
__global__ __launch_bounds__(256) void aggregate10_kernel(
    const unsigned short* __restrict__ vh, const unsigned short* __restrict__ scores,
    const unsigned* __restrict__ sdp, const int* __restrict__ offs,
    const float* __restrict__ headmax, unsigned short* __restrict__ aggb,
    float* __restrict__ psum_part)
{
    __shared__ int sSrc[512];
    __shared__ float sP[512];
    __shared__ float blocksum;
    int tid = threadIdx.x;
    int h = blockIdx.x & 7;
    int chunk = blockIdx.x >> 3;
    int nodebase = chunk * 32;
    int g = tid >> 3;
    int ln = tid & 7;
    int node = nodebase + g;
    float m = headmax[h];
    const unsigned short* sc_h = scores + (size_t)h * NUM_EDGES;
    const unsigned short* vhh = vh + (size_t)h * NUM_NODES * 32;
    if (tid == 0) blocksum = 0.f;

    int blkstart = offs[nodebase];
    int blkend = offs[(nodebase + 32 < NUM_NODES) ? (nodebase + 32) : NUM_NODES];
    int start = 0, end = 0;
    if (node < NUM_NODES) { start = offs[node]; end = offs[node + 1]; }

    f32x4 a0 = (f32x4)(0.f), a1 = (f32x4)(0.f);
    float ps = 0.f;

    for (int t0 = blkstart; t0 < blkend; t0 += 512) {
        int cnt = min(512, blkend - t0);
        __syncthreads();
        for (int i = tid; i < cnt; i += 256) {
            sSrc[i] = (int)(sdp[t0 + i] & 0xffffu);
            float p = __expf(h2f(sc_h[t0 + i]) - m);
            sP[i] = p;
            ps += p;
        }
        __syncthreads();
        int lo = (start > t0) ? start : t0;
        int hi = (end < t0 + cnt) ? end : (t0 + cnt);
        int cb = lo;
        for (; cb + 2 <= hi; cb += 2) {
            int i0 = cb - t0;
            int s0 = sSrc[i0], s1 = sSrc[i0 + 1];
            float p0 = sP[i0], p1 = sP[i0 + 1];
            ushort4 v0 = *(const ushort4*)(vhh + (size_t)s0 * 32 + ln * 4);
            ushort4 v1 = *(const ushort4*)(vhh + (size_t)s1 * 32 + ln * 4);
            a0[0] += p0 * bf2f(v0.x); a0[1] += p0 * bf2f(v0.y);
            a0[2] += p0 * bf2f(v0.z); a0[3] += p0 * bf2f(v0.w);
            a1[0] += p1 * bf2f(v1.x); a1[1] += p1 * bf2f(v1.y);
            a1[2] += p1 * bf2f(v1.z); a1[3] += p1 * bf2f(v1.w);
        }
        if (cb < hi) {
            int i0 = cb - t0;
            int s0 = sSrc[i0];
            float p0 = sP[i0];
            ushort4 v0 = *(const ushort4*)(vhh + (size_t)s0 * 32 + ln * 4);
            a0[0] += p0 * bf2f(v0.x); a0[1] += p0 * bf2f(v0.y);
            a0[2] += p0 * bf2f(v0.z); a0[3] += p0 * bf2f(v0.w);
        }
    }

    if (node < NUM_NODES) {
        ushort4 o;
        o.x = f2bf(a0[0] + a1[0]); o.y = f2bf(a0[1] + a1[1]);
        o.z = f2bf(a0[2] + a1[2]); o.w = f2bf(a0[3] + a1[3]);
        *(ushort4*)(aggb + ((size_t)h * NUM_NODES + node) * 32 + ln * 4) = o;
    }

    __syncthreads();
#pragma unroll
    for (int off = 32; off > 0; off >>= 1) ps += __shfl_xor(ps, off, 64);
    if ((tid & 63) == 0) atomicAdd(&blocksum, ps);
    __syncthreads();
    if (tid == 0) psum_part[blockIdx.x] = blocksum;
}

__global__ __launch_bounds__(256) void reduce_psum2_kernel(
    const float* __restrict__ psum_part, float* __restrict__ headinv)
{
    int tid = threadIdx.x;
    int h = tid >> 5, lane = tid & 31;
    float s = 0.f;
    for (int i = lane; i < NCHUNK32; i += 32) s += psum_part[i * 8 + h];
    for (int off = 16; off > 0; off >>= 1) s += __shfl_down(s, off, 32);
    if (lane == 0) headinv[h] = 1.f / s;
}

extern "C" void kernel_launch(void* const* d_in, const int* in_sizes, int n_in,
                              void* d_out, int out_size, void* d_ws, size_t ws_size,
                              hipStream_t stream) {
    const float* x = (const float*)d_in[0];
    const int* ei = (const int*)d_in[1];
    const int* src_idx = ei;
    const int* dst_idx = ei + NUM_EDGES;
    const float* edge_time = (const float*)d_in[2];
    const float* node_time = (const float*)d_in[3];
    const float* Wq = (const float*)d_in[4];  const float* bq = (const float*)d_in[5];
    const float* Wk = (const float*)d_in[6];  const float* bk = (const float*)d_in[7];
    const float* Wv = (const float*)d_in[8];  const float* bv = (const float*)d_in[9];
    const float* Wt = (const float*)d_in[10]; const float* bt = (const float*)d_in[11];
    const float* Wo = (const float*)d_in[12]; const float* bo = (const float*)d_in[13];
    float* out = (float*)d_out;

    char* w = (char*)d_ws;
    unsigned short* qb = (unsigned short*)w; w += (size_t)NUM_NODES * 256 * 2;  // [8][N][32] f16
    unsigned short* kb = (unsigned short*)w; w += (size_t)NUM_NODES * 256 * 2;  // [8][N][32] f16
    unsigned short* vb = (unsigned short*)w; w += (size_t)NUM_NODES * 256 * 2;  // [8][N][32] bf16
    unsigned short* scores = (unsigned short*)w; w += (size_t)NUM_EDGES * 8 * 2; // [8][E] f16
    unsigned short* aggb = (unsigned short*)w; w += (size_t)NUM_NODES * 256 * 2; // [8][N][32]
    unsigned* sdp = (unsigned*)w;   w += (size_t)NUM_EDGES * 4;
    unsigned* tfh = (unsigned*)w;   w += (size_t)NUM_EDGES * 4;
    int* edge_of = (int*)w;         w += (size_t)NUM_EDGES * 4;
    int* deg = (int*)w;             w += (size_t)NUM_NODES * 4;
    int* offs = (int*)w;            w += (size_t)(NUM_NODES + 1) * 4;
    int* cursor = (int*)w;          w += (size_t)NUM_NODES * 4;
    unsigned* partialmax = (unsigned*)w; w += 2048 * 4;
    float* psum_part = (float*)w;   w += (size_t)NCHUNK32 * 8 * 4;
    float* headmax = (float*)w;     w += 8 * 4;
    float* headinv = (float*)w;     w += 8 * 4;
    int* blocksum = (int*)w;        w += 64 * 4;
    int* bcarry = (int*)w;          w += 64 * 4;
    unsigned short* Wtb = (unsigned short*)w; w += (size_t)1024 * 256 * 2;
    unsigned short* Wpk = (unsigned short*)w; w += (size_t)1024 * 256 * 2;

    hipMemsetAsync(deg, 0, (size_t)NUM_NODES * 4, stream);

    // weight transpose + bf16 cvt, then fragment-pack
    dim3 gw(16, 4);
    wtrans_kernel<<<gw, 256, 0, stream>>>(Wq, Wk, Wv, Wo, Wtb);
    wpack_kernel<<<128, 256, 0, stream>>>(Wtb, Wpk);

    // CSR by dst (parallel scan); minimal scatter then gather-fill
    deg_kernel<<<(NUM_EDGES + 255) / 256, 256, 0, stream>>>(dst_idx, deg);
    scanA_kernel<<<SCAN_BLOCKS, 1024, 0, stream>>>(deg, offs, blocksum);
    scanB_kernel<<<1, 64, 0, stream>>>(blocksum, bcarry, offs);
    scanC_kernel<<<(NUM_NODES + 255) / 256, 256, 0, stream>>>(offs, bcarry, cursor);
    fillA_kernel<<<(NUM_EDGES + 255) / 256, 256, 0, stream>>>(dst_idx, cursor, edge_of);
    fillB_kernel<<<(NUM_EDGES + 255) / 256, 256, 0, stream>>>(
        edge_of, src_idx, dst_idx, edge_time, node_time, sdp, tfh);

    // QKV projection -> head-major q/k (f16) + v (bf16)
    gemm_qkv_mfma7<<<(NUM_NODES + 63) / 64, 256, 0, stream>>>(
        x, NUM_NODES, Wpk, bq, bk, bv, qb, kb, vb);

    // scores (head-pinned, lane-quad gathers, fdot2) + per-head max
    score7_kernel<<<2048, 256, 0, stream>>>(qb, kb, sdp, tfh, Wt, bt, scores, partialmax);
    reduce_max3_kernel<<<1, 256, 0, stream>>>(partialmax, headmax);

    // aggregate (head-pinned, LDS-staged src+p, inline exp) + psum partials
    aggregate10_kernel<<<NCHUNK32 * 8, 256, 0, stream>>>(
        vb, scores, sdp, offs, headmax, aggb, psum_part);
    reduce_psum2_kernel<<<1, 256, 0, stream>>>(psum_part, headinv);

    // output projection with per-head 1/sum folded into staging (packed-W)
    gemm_out_mfma6<<<(NUM_NODES + 63) / 64, 256, 0, stream>>>(
        aggb, NUM_NODES, Wpk + (size_t)768 * 256, bo, headinv, out);
}

// Round 18
// 361.201 us; speedup vs baseline: 1.0602x; 1.0579x over previous
//
#include <hip/hip_runtime.h>
#include <hip/hip_bf16.h>

#define NUM_NODES 50000
#define NUM_EDGES 800000
#define NUM_HEADS 8
#define HEAD_DIM 32
#define SCAN_BLOCKS 49
#define NCHUNK32 1563   // ceil(50000/32)

typedef unsigned short ushort8 __attribute__((ext_vector_type(8)));
typedef float f32x4 __attribute__((ext_vector_type(4)));
typedef __bf16 bf16x8 __attribute__((ext_vector_type(8)));
typedef _Float16 h2 __attribute__((ext_vector_type(2)));

union BF8 { ushort8 u; bf16x8 b; };
union H8 { ushort8 u; h2 h[4]; };

#if defined(__has_builtin)
#if __has_builtin(__builtin_amdgcn_fdot2)
#define FDOT2(a, b, c) __builtin_amdgcn_fdot2((a), (b), (c), false)
#endif
#endif
#ifndef FDOT2
#define FDOT2(a, b, c) ((float)(a)[0] * (float)(b)[0] + (float)(a)[1] * (float)(b)[1] + (c))
#endif

__device__ __forceinline__ float bf2f(unsigned short u) {
    return __uint_as_float(((unsigned)u) << 16);
}
__device__ __forceinline__ unsigned short f2bf(float f) {
    unsigned u = __float_as_uint(f);
    unsigned r = (u + 0x7fffu + ((u >> 16) & 1u)) >> 16;
    return (unsigned short)r;
}
__device__ __forceinline__ unsigned short f2h(float f) {
    _Float16 h = (_Float16)f;
    return *(unsigned short*)&h;
}
__device__ __forceinline__ float h2f(unsigned short u) {
    _Float16 h = *(const _Float16*)&u;
    return (float)h;
}

// ---------- CSR build ----------
__global__ __launch_bounds__(256) void deg_kernel(const int* __restrict__ dst_idx, int* __restrict__ deg) {
    int e = blockIdx.x * 256 + threadIdx.x;
    if (e < NUM_EDGES) atomicAdd(&deg[dst_idx[e]], 1);
}

__global__ __launch_bounds__(1024) void scanA_kernel(
    const int* __restrict__ deg, int* __restrict__ offs, int* __restrict__ blocksum)
{
    __shared__ int buf[1024];
    int tid = threadIdx.x;
    int i = blockIdx.x * 1024 + tid;
    int v = (i < NUM_NODES) ? deg[i] : 0;
    buf[tid] = v;
    __syncthreads();
    for (int off = 1; off < 1024; off <<= 1) {
        int t = (tid >= off) ? buf[tid - off] : 0;
        __syncthreads();
        buf[tid] += t;
        __syncthreads();
    }
    if (i < NUM_NODES) offs[i] = buf[tid] - v;
    if (tid == 1023) blocksum[blockIdx.x] = buf[1023];
}

__global__ __launch_bounds__(64) void scanB_kernel(
    const int* __restrict__ blocksum, int* __restrict__ carry, int* __restrict__ offs)
{
    if (threadIdx.x == 0) {
        int acc = 0;
        for (int b = 0; b < SCAN_BLOCKS; b++) { carry[b] = acc; acc += blocksum[b]; }
        offs[NUM_NODES] = acc;
    }
}

__global__ __launch_bounds__(256) void scanC_kernel(
    int* __restrict__ offs, const int* __restrict__ carry, int* __restrict__ cursor)
{
    int i = blockIdx.x * 256 + threadIdx.x;
    if (i < NUM_NODES) {
        int v = offs[i] + carry[i >> 10];
        offs[i] = v;
        cursor[i] = v;
    }
}

// scatter ONLY edge_of (4B)
__global__ __launch_bounds__(256) void fillA_kernel(
    const int* __restrict__ dst_idx, int* __restrict__ cursor, int* __restrict__ edge_of)
{
    int e = blockIdx.x * 256 + threadIdx.x;
    if (e < NUM_EDGES) {
        int pos = atomicAdd(&cursor[dst_idx[e]], 1);
        edge_of[pos] = e;
    }
}

// gather pass: edata = { s|(d<<16) } | { f16(t0)|f16(t1)<<16 } << 32, coalesced NT write
__global__ __launch_bounds__(256) void fillB_kernel(
    const int* __restrict__ edge_of,
    const int* __restrict__ src_idx, const int* __restrict__ dst_idx,
    const float* __restrict__ edge_time, const float* __restrict__ node_time,
    unsigned long long* __restrict__ edata)
{
    int pos = blockIdx.x * 256 + threadIdx.x;
    if (pos < NUM_EDGES) {
        int e = __builtin_nontemporal_load(&edge_of[pos]);
        int s = src_idx[e];
        int d = dst_idx[e];
        float td = edge_time[e] - node_time[d];
        float t0 = (td > 0.f) ? 1.f : ((td < 0.f) ? -1.f : 0.f);
        float t1 = log1pf(fabsf(td) * (1.f / 3600.f));
        unsigned lo = (unsigned)s | ((unsigned)d << 16);
        unsigned hi = (unsigned)f2h(t0) | ((unsigned)f2h(t1) << 16);
        unsigned long long v = (unsigned long long)lo | ((unsigned long long)hi << 32);
        __builtin_nontemporal_store(v, &edata[pos]);
    }
}

// ---------- weight transpose+cvt: Wt[1024 n][256 k] bf16 ----------
__global__ __launch_bounds__(256) void wtrans_kernel(
    const float* __restrict__ Wq, const float* __restrict__ Wk,
    const float* __restrict__ Wv, const float* __restrict__ Wo,
    unsigned short* __restrict__ Wt)
{
    __shared__ float t[64][65];
    int nb = blockIdx.x * 64;
    int kb = blockIdx.y * 64;
    int g = nb >> 8;
    const float* W = (g == 0) ? Wq : (g == 1) ? Wk : (g == 2) ? Wv : Wo;
    int n0 = nb & 255;
    int tx = threadIdx.x & 63;
    int ty = threadIdx.x >> 6;
#pragma unroll
    for (int i = 0; i < 16; i++) {
        int k = i * 4 + ty;
        t[tx][k] = W[(size_t)(kb + k) * 256 + n0 + tx];
    }
    __syncthreads();
#pragma unroll
    for (int i = 0; i < 16; i++) {
        int n = i * 4 + ty;
        Wt[(size_t)(nb + n) * 256 + kb + tx] = f2bf(t[n][tx]);
    }
}

// ---------- pack W into MFMA fragment order ----------
__global__ __launch_bounds__(256) void wpack_kernel(
    const unsigned short* __restrict__ Wt, unsigned short* __restrict__ Wpk)
{
    int gid = blockIdx.x * 256 + threadIdx.x;
    int lane = gid & 63;
    int fragidx = gid >> 6;
    int c2 = fragidx & 7;
    int nf = (fragidx >> 3) & 3;
    int cb = (fragidx >> 5) & 3;
    int g = fragidx >> 7;
    int l16 = lane & 15;
    int kg = lane >> 4;
    int n_col = g * 256 + cb * 64 + nf * 16 + l16;
    int k0 = c2 * 32 + kg * 8;
    ushort8 v = *(const ushort8*)(Wt + (size_t)n_col * 256 + k0);
    *(ushort8*)(Wpk + (size_t)gid * 8) = v;
}

// ---------- QKV GEMM via MFMA (q,k f16; v bf16; head-major) ----------
__global__ __launch_bounds__(256) void gemm_qkv_mfma7(
    const float* __restrict__ A, int M,
    const unsigned short* __restrict__ Wpk,
    const float* __restrict__ b0, const float* __restrict__ b1, const float* __restrict__ b2,
    unsigned short* __restrict__ O0, unsigned short* __restrict__ O1, unsigned short* __restrict__ O2)
{
    __shared__ unsigned short As[64 * 256];
    int tid = threadIdx.x;
    int rowbase = blockIdx.x * 64;

    {
        int rsub = tid >> 6;
        int c4 = (tid & 63) * 4;
        int cchunk = (tid & 63) >> 1;
        int sub = (tid & 1);
#pragma unroll
        for (int it = 0; it < 16; it++) {
            int row = it * 4 + rsub;
            int grow = rowbase + row;
            float4 av = make_float4(0.f, 0.f, 0.f, 0.f);
            if (grow < M) av = *(const float4*)(A + (size_t)grow * 256 + c4);
            ushort4 o;
            o.x = f2bf(av.x); o.y = f2bf(av.y); o.z = f2bf(av.z); o.w = f2bf(av.w);
            unsigned byte = row * 512 + ((unsigned)(cchunk ^ (row & 7)) << 4) + sub * 8;
            *(ushort4*)((char*)As + byte) = o;
        }
    }
    __syncthreads();

    int lane = tid & 63;
    int wid = tid >> 6;
    int l16 = lane & 15;
    int kg = lane >> 4;

#pragma unroll
    for (int p = 0; p < 3; p++) {
        const float* bias = (p == 0) ? b0 : (p == 1) ? b1 : b2;
        unsigned short* O = (p == 0) ? O0 : (p == 1) ? O1 : O2;

        f32x4 acc[4][4];
#pragma unroll
        for (int m = 0; m < 4; m++)
#pragma unroll
            for (int n = 0; n < 4; n++) acc[m][n] = (f32x4)(0.0f);

        const ushort8* wbase = (const ushort8*)(Wpk + ((size_t)(p * 4 + wid) * 2048 + lane) * 8);

#pragma unroll
        for (int c2 = 0; c2 < 8; c2++) {
            bf16x8 wfr[4];
#pragma unroll
            for (int n = 0; n < 4; n++) {
                BF8 t; t.u = wbase[(n * 8 + c2) * 64];
                wfr[n] = t.b;
            }
            bf16x8 afr[4];
#pragma unroll
            for (int m = 0; m < 4; m++) {
                int row = m * 16 + l16;
                int cchunk = (c2 * 4 + kg) ^ (row & 7);
                BF8 t;
                t.u = *(const ushort8*)((const char*)As + row * 512 + (cchunk << 4));
                afr[m] = t.b;
            }
#pragma unroll
            for (int m = 0; m < 4; m++)
#pragma unroll
                for (int n = 0; n < 4; n++)
                    acc[m][n] = __builtin_amdgcn_mfma_f32_16x16x32_bf16(wfr[n], afr[m], acc[m][n], 0, 0, 0);
        }

#pragma unroll
        for (int m = 0; m < 4; m++) {
            int node = rowbase + m * 16 + l16;
            if (node >= M) continue;
#pragma unroll
            for (int n = 0; n < 4; n++) {
                int lc = wid * 64 + n * 16 + kg * 4;
                float4 bv = *(const float4*)(bias + lc);
                ushort4 o;
                if (p < 2) {
                    o.x = f2h(acc[m][n][0] + bv.x);
                    o.y = f2h(acc[m][n][1] + bv.y);
                    o.z = f2h(acc[m][n][2] + bv.z);
                    o.w = f2h(acc[m][n][3] + bv.w);
                } else {
                    o.x = f2bf(acc[m][n][0] + bv.x);
                    o.y = f2bf(acc[m][n][1] + bv.y);
                    o.z = f2bf(acc[m][n][2] + bv.z);
                    o.w = f2bf(acc[m][n][3] + bv.w);
                }
                int hh = lc >> 5, dd = lc & 31;
                *(ushort4*)(O + ((size_t)hh * NUM_NODES + node) * 32 + dd) = o;
            }
        }
    }
}

// ---------- output GEMM, packed-W; per-head scale in staging ----------
__global__ __launch_bounds__(256) void gemm_out_mfma6(
    const unsigned short* __restrict__ aggb, int M,
    const unsigned short* __restrict__ Wpk,
    const float* __restrict__ bias, const float* __restrict__ kscale,
    float* __restrict__ C)
{
    __shared__ unsigned short As[64 * 256];
    int tid = threadIdx.x;
    int rowbase = blockIdx.x * 64;

    {
        int rsub = tid >> 6;
        int c4 = (tid & 63) * 4;
        int cchunk = (tid & 63) >> 1;
        int sub = (tid & 1);
        int hh = c4 >> 5, dd = c4 & 31;
        float ks = kscale[hh];
#pragma unroll
        for (int it = 0; it < 16; it++) {
            int row = it * 4 + rsub;
            int grow = rowbase + row;
            ushort4 av = make_ushort4(0, 0, 0, 0);
            if (grow < M) av = *(const ushort4*)(aggb + ((size_t)hh * NUM_NODES + grow) * 32 + dd);
            ushort4 o;
            o.x = f2bf(bf2f(av.x) * ks); o.y = f2bf(bf2f(av.y) * ks);
            o.z = f2bf(bf2f(av.z) * ks); o.w = f2bf(bf2f(av.w) * ks);
            unsigned byte = row * 512 + ((unsigned)(cchunk ^ (row & 7)) << 4) + sub * 8;
            *(ushort4*)((char*)As + byte) = o;
        }
    }
    __syncthreads();

    int lane = tid & 63;
    int wid = tid >> 6;
    int l16 = lane & 15;
    int kg = lane >> 4;

    f32x4 acc[4][4];
#pragma unroll
    for (int m = 0; m < 4; m++)
#pragma unroll
        for (int n = 0; n < 4; n++) acc[m][n] = (f32x4)(0.0f);

    const ushort8* wbase = (const ushort8*)(Wpk + ((size_t)wid * 2048 + lane) * 8);

#pragma unroll
    for (int c2 = 0; c2 < 8; c2++) {
        bf16x8 wfr[4];
#pragma unroll
        for (int n = 0; n < 4; n++) {
            BF8 t; t.u = wbase[(n * 8 + c2) * 64];
            wfr[n] = t.b;
        }
        bf16x8 afr[4];
#pragma unroll
        for (int m = 0; m < 4; m++) {
            int row = m * 16 + l16;
            int cchunk = (c2 * 4 + kg) ^ (row & 7);
            BF8 t;
            t.u = *(const ushort8*)((const char*)As + row * 512 + (cchunk << 4));
            afr[m] = t.b;
        }
#pragma unroll
        for (int m = 0; m < 4; m++)
#pragma unroll
            for (int n = 0; n < 4; n++)
                acc[m][n] = __builtin_amdgcn_mfma_f32_16x16x32_bf16(wfr[n], afr[m], acc[m][n], 0, 0, 0);
    }

#pragma unroll
    for (int m = 0; m < 4; m++) {
        int node = rowbase + m * 16 + l16;
        if (node >= M) continue;
#pragma unroll
        for (int n = 0; n < 4; n++) {
            int col = wid * 64 + n * 16 + kg * 4;
            float4 bv = *(const float4*)(bias + col);
            float4 o;
            o.x = acc[m][n][0] + bv.x;
            o.y = acc[m][n][1] + bv.y;
            o.z = acc[m][n][2] + bv.z;
            o.w = acc[m][n][3] + bv.w;
            *(float4*)(C + (size_t)node * 256 + col) = o;
        }
    }
}

// ---------- FUSED edge phase: score + exp (no-max softmax) + aggregate + psum ----------
// block = 32 dst nodes x 1 head (head-pinned). Staging threads compute p=exp(score)
// inline into LDS; inner loop: 4-lane x 2-edge groups, 16B v-gathers.
__global__ __launch_bounds__(256) void edge_fused_kernel(
    const unsigned short* __restrict__ qh, const unsigned short* __restrict__ kh,
    const unsigned short* __restrict__ vh, const unsigned long long* __restrict__ edata,
    const int* __restrict__ offs, const float* __restrict__ Wt,
    const float* __restrict__ bt, unsigned short* __restrict__ aggb,
    float* __restrict__ psum_part)
{
    __shared__ int sSrc[512];
    __shared__ float sP[512];
    __shared__ float blocksum;
    int tid = threadIdx.x;
    int h = blockIdx.x & 7;
    int chunk = blockIdx.x >> 3;
    int nodebase = chunk * 32;
    float wt0 = Wt[h], wt1 = Wt[8 + h], btv = bt[h];
    const unsigned short* qhh = qh + (size_t)h * NUM_NODES * 32;
    const unsigned short* khh = kh + (size_t)h * NUM_NODES * 32;
    const unsigned short* vhh = vh + (size_t)h * NUM_NODES * 32;
    if (tid == 0) blocksum = 0.f;

    int gg = tid >> 3;          // 0..31: node within chunk
    int j = (tid >> 2) & 1;     // edge parity within group
    int ln4 = tid & 3;          // 16B slot (8 dims)
    int node = nodebase + gg;

    int blkstart = offs[nodebase];
    int nb_hi = (nodebase + 32 < NUM_NODES) ? (nodebase + 32) : NUM_NODES;
    int blkend = offs[nb_hi];
    int start = 0, end = 0;
    if (node < NUM_NODES) { start = offs[node]; end = offs[node + 1]; }

    f32x4 a0 = (f32x4)(0.f), a1 = (f32x4)(0.f);
    float ps = 0.f;

    for (int t0 = blkstart; t0 < blkend; t0 += 512) {
        int cnt = min(512, blkend - t0);
        __syncthreads();
        // staging: compute p = exp(score) inline (no max; scores bounded)
        for (int i = tid; i < cnt; i += 256) {
            unsigned long long ed = __builtin_nontemporal_load(&edata[t0 + i]);
            unsigned lo32 = (unsigned)(ed & 0xffffffffull);
            unsigned hi32 = (unsigned)(ed >> 32);
            int s = lo32 & 0xffffu;
            int d = lo32 >> 16;
            float tf0 = h2f((unsigned short)(hi32 & 0xffffu));
            float tf1 = h2f((unsigned short)(hi32 >> 16));
            const ushort8* kp = (const ushort8*)(khh + (size_t)s * 32);
            const ushort8* qp = (const ushort8*)(qhh + (size_t)d * 32);
            float dotv = 0.f;
#pragma unroll
            for (int u = 0; u < 4; u++) {
                H8 a, b;
                a.u = qp[u]; b.u = kp[u];
#pragma unroll
                for (int jj = 0; jj < 4; jj++) dotv = FDOT2(a.h[jj], b.h[jj], dotv);
            }
            float sc = dotv * 0.17677669529663687f + (tf0 * wt0 + tf1 * wt1 + btv);
            sc = fminf(sc, 80.f);
            float p = __expf(sc);
            sSrc[i] = s;
            sP[i] = p;
            ps += p;
        }
        __syncthreads();
        // aggregation: this group's slice of the tile
        int lo = (start > t0) ? start : t0;
        int hi = (end < t0 + cnt) ? end : (t0 + cnt);
        for (int cb = lo + j; cb < hi; cb += 2) {
            int i0 = cb - t0;
            int s0 = sSrc[i0];
            float p0 = sP[i0];
            ushort8 v = *(const ushort8*)(vhh + (size_t)s0 * 32 + ln4 * 8);
            a0[0] += p0 * bf2f(v[0]); a0[1] += p0 * bf2f(v[1]);
            a0[2] += p0 * bf2f(v[2]); a0[3] += p0 * bf2f(v[3]);
            a1[0] += p0 * bf2f(v[4]); a1[1] += p0 * bf2f(v[5]);
            a1[2] += p0 * bf2f(v[6]); a1[3] += p0 * bf2f(v[7]);
        }
    }

    // combine the two edge-parity partials (lanes differing in bit 2)
#pragma unroll
    for (int i = 0; i < 4; i++) {
        a0[i] += __shfl_xor(a0[i], 4, 64);
        a1[i] += __shfl_xor(a1[i], 4, 64);
    }
    if (node < NUM_NODES && j == 0) {
        ushort8 o;
        o[0] = f2bf(a0[0]); o[1] = f2bf(a0[1]); o[2] = f2bf(a0[2]); o[3] = f2bf(a0[3]);
        o[4] = f2bf(a1[0]); o[5] = f2bf(a1[1]); o[6] = f2bf(a1[2]); o[7] = f2bf(a1[3]);
        *(ushort8*)(aggb + ((size_t)h * NUM_NODES + node) * 32 + ln4 * 8) = o;
    }

    __syncthreads();
#pragma unroll
    for (int off = 32; off > 0; off >>= 1) ps += __shfl_xor(ps, off, 64);
    if ((tid & 63) == 0) atomicAdd(&blocksum, ps);
    __syncthreads();
    if (tid == 0) psum_part[blockIdx.x] = blocksum;
}

// psum_part[NCHUNK32*8], entry i belongs to head i&7
__global__ __launch_bounds__(256) void reduce_psum2_kernel(
    const float* __restrict__ psum_part, float* __restrict__ headinv)
{
    int tid = threadIdx.x;
    int h = tid >> 5, lane = tid & 31;
    float s = 0.f;
    for (int i = lane; i < NCHUNK32; i += 32) s += psum_part[i * 8 + h];
    for (int off = 16; off > 0; off >>= 1) s += __shfl_down(s, off, 32);
    if (lane == 0) headinv[h] = 1.f / s;
}

extern "C" void kernel_launch(void* const* d_in, const int* in_sizes, int n_in,
                              void* d_out, int out_size, void* d_ws, size_t ws_size,
                              hipStream_t stream) {
    const float* x = (const float*)d_in[0];
    const int* ei = (const int*)d_in[1];
    const int* src_idx = ei;
    const int* dst_idx = ei + NUM_EDGES;
    const float* edge_time = (const float*)d_in[2];
    const float* node_time = (const float*)d_in[3];
    const float* Wq = (const float*)d_in[4];  const float* bq = (const float*)d_in[5];
    const float* Wk = (const float*)d_in[6];  const float* bk = (const float*)d_in[7];
    const float* Wv = (const float*)d_in[8];  const float* bv = (const float*)d_in[9];
    const float* Wt = (const float*)d_in[10]; const float* bt = (const float*)d_in[11];
    const float* Wo = (const float*)d_in[12]; const float* bo = (const float*)d_in[13];
    float* out = (float*)d_out;

    char* w = (char*)d_ws;
    unsigned short* qb = (unsigned short*)w; w += (size_t)NUM_NODES * 256 * 2;  // [8][N][32] f16
    unsigned short* kb = (unsigned short*)w; w += (size_t)NUM_NODES * 256 * 2;  // [8][N][32] f16
    unsigned short* vb = (unsigned short*)w; w += (size_t)NUM_NODES * 256 * 2;  // [8][N][32] bf16
    unsigned short* aggb = (unsigned short*)w; w += (size_t)NUM_NODES * 256 * 2; // [8][N][32]
    unsigned long long* edata = (unsigned long long*)w; w += (size_t)NUM_EDGES * 8;
    int* edge_of = (int*)w;         w += (size_t)NUM_EDGES * 4;
    int* deg = (int*)w;             w += (size_t)NUM_NODES * 4;
    int* offs = (int*)w;            w += (size_t)(NUM_NODES + 1) * 4;
    int* cursor = (int*)w;          w += (size_t)NUM_NODES * 4;
    float* psum_part = (float*)w;   w += (size_t)NCHUNK32 * 8 * 4;
    float* headinv = (float*)w;     w += 8 * 4;
    int* blocksum = (int*)w;        w += 64 * 4;
    int* bcarry = (int*)w;          w += 64 * 4;
    unsigned short* Wtb = (unsigned short*)w; w += (size_t)1024 * 256 * 2;
    unsigned short* Wpk = (unsigned short*)w; w += (size_t)1024 * 256 * 2;

    hipMemsetAsync(deg, 0, (size_t)NUM_NODES * 4, stream);

    // weight transpose + bf16 cvt, then fragment-pack
    dim3 gw(16, 4);
    wtrans_kernel<<<gw, 256, 0, stream>>>(Wq, Wk, Wv, Wo, Wtb);
    wpack_kernel<<<128, 256, 0, stream>>>(Wtb, Wpk);

    // CSR by dst (parallel scan); minimal scatter then gather-fill
    deg_kernel<<<(NUM_EDGES + 255) / 256, 256, 0, stream>>>(dst_idx, deg);
    scanA_kernel<<<SCAN_BLOCKS, 1024, 0, stream>>>(deg, offs, blocksum);
    scanB_kernel<<<1, 64, 0, stream>>>(blocksum, bcarry, offs);
    scanC_kernel<<<(NUM_NODES + 255) / 256, 256, 0, stream>>>(offs, bcarry, cursor);
    fillA_kernel<<<(NUM_EDGES + 255) / 256, 256, 0, stream>>>(dst_idx, cursor, edge_of);
    fillB_kernel<<<(NUM_EDGES + 255) / 256, 256, 0, stream>>>(
        edge_of, src_idx, dst_idx, edge_time, node_time, edata);

    // QKV projection -> head-major q/k (f16) + v (bf16)
    gemm_qkv_mfma7<<<(NUM_NODES + 63) / 64, 256, 0, stream>>>(
        x, NUM_NODES, Wpk, bq, bk, bv, qb, kb, vb);

    // FUSED edge phase: score + exp + aggregate + per-head sum partials
    edge_fused_kernel<<<NCHUNK32 * 8, 256, 0, stream>>>(
        qb, kb, vb, edata, offs, Wt, bt, aggb, psum_part);
    reduce_psum2_kernel<<<1, 256, 0, stream>>>(psum_part, headinv);

    // output projection with per-head 1/sum folded into staging (packed-W)
    gemm_out_mfma6<<<(NUM_NODES + 63) / 64, 256, 0, stream>>>(
        aggb, NUM_NODES, Wpk + (size_t)768 * 256, bo, headinv, out);
}

// Round 19
// 361.181 us; speedup vs baseline: 1.0603x; 1.0001x over previous
//
#include <hip/hip_runtime.h>
#include <hip/hip_bf16.h>

#define NUM_NODES 50000
#define NUM_EDGES 800000
#define NUM_HEADS 8
#define HEAD_DIM 32
#define SCAN_BLOCKS 49
#define NCHUNK32 1563   // ceil(50000/32)

typedef unsigned short ushort8 __attribute__((ext_vector_type(8)));
typedef float f32x4 __attribute__((ext_vector_type(4)));
typedef __bf16 bf16x8 __attribute__((ext_vector_type(8)));
typedef _Float16 h2 __attribute__((ext_vector_type(2)));

union BF8 { ushort8 u; bf16x8 b; };
union H8 { ushort8 u; h2 h[4]; };

#if defined(__has_builtin)
#if __has_builtin(__builtin_amdgcn_fdot2)
#define FDOT2(a, b, c) __builtin_amdgcn_fdot2((a), (b), (c), false)
#endif
#endif
#ifndef FDOT2
#define FDOT2(a, b, c) ((float)(a)[0] * (float)(b)[0] + (float)(a)[1] * (float)(b)[1] + (c))
#endif

__device__ __forceinline__ unsigned float_to_key(float f) {
    int i = __float_as_int(f);
    return (i >= 0) ? ((unsigned)i | 0x80000000u) : ~(unsigned)i;
}
__device__ __forceinline__ float key_to_float(unsigned u) {
    unsigned b = (u & 0x80000000u) ? (u & 0x7fffffffu) : ~u;
    return __int_as_float((int)b);
}
__device__ __forceinline__ float bf2f(unsigned short u) {
    return __uint_as_float(((unsigned)u) << 16);
}
__device__ __forceinline__ unsigned short f2bf(float f) {
    unsigned u = __float_as_uint(f);
    unsigned r = (u + 0x7fffu + ((u >> 16) & 1u)) >> 16;
    return (unsigned short)r;
}
__device__ __forceinline__ unsigned short f2h(float f) {
    _Float16 h = (_Float16)f;
    return *(unsigned short*)&h;
}

// ---------- CSR build ----------
__global__ __launch_bounds__(256) void deg_kernel(const int* __restrict__ dst_idx, int* __restrict__ deg) {
    int e = blockIdx.x * 256 + threadIdx.x;
    if (e < NUM_EDGES) atomicAdd(&deg[dst_idx[e]], 1);
}

__global__ __launch_bounds__(1024) void scanA_kernel(
    const int* __restrict__ deg, int* __restrict__ offs, int* __restrict__ blocksum)
{
    __shared__ int buf[1024];
    int tid = threadIdx.x;
    int i = blockIdx.x * 1024 + tid;
    int v = (i < NUM_NODES) ? deg[i] : 0;
    buf[tid] = v;
    __syncthreads();
    for (int off = 1; off < 1024; off <<= 1) {
        int t = (tid >= off) ? buf[tid - off] : 0;
        __syncthreads();
        buf[tid] += t;
        __syncthreads();
    }
    if (i < NUM_NODES) offs[i] = buf[tid] - v;
    if (tid == 1023) blocksum[blockIdx.x] = buf[1023];
}

__global__ __launch_bounds__(64) void scanB_kernel(
    const int* __restrict__ blocksum, int* __restrict__ carry, int* __restrict__ offs)
{
    if (threadIdx.x == 0) {
        int acc = 0;
        for (int b = 0; b < SCAN_BLOCKS; b++) { carry[b] = acc; acc += blocksum[b]; }
        offs[NUM_NODES] = acc;
    }
}

__global__ __launch_bounds__(256) void scanC_kernel(
    int* __restrict__ offs, const int* __restrict__ carry, int* __restrict__ cursor)
{
    int i = blockIdx.x * 256 + threadIdx.x;
    if (i < NUM_NODES) {
        int v = offs[i] + carry[i >> 10];
        offs[i] = v;
        cursor[i] = v;
    }
}

// scatter ONLY edge_of (4B) — minimal scattered writes
__global__ __launch_bounds__(256) void fillA_kernel(
    const int* __restrict__ dst_idx, int* __restrict__ cursor, int* __restrict__ edge_of)
{
    int e = blockIdx.x * 256 + threadIdx.x;
    if (e < NUM_EDGES) {
        int pos = atomicAdd(&cursor[dst_idx[e]], 1);
        edge_of[pos] = e;
    }
}

// gather pass: coalesced read edge_of, gather inputs (L2-resident), coalesced writes
__global__ __launch_bounds__(256) void fillB_kernel(
    const int* __restrict__ edge_of,
    const int* __restrict__ src_idx, const int* __restrict__ dst_idx,
    const float* __restrict__ edge_time, const float* __restrict__ node_time,
    int2* __restrict__ sd, float2* __restrict__ tf, int* __restrict__ src_s)
{
    int pos = blockIdx.x * 256 + threadIdx.x;
    if (pos < NUM_EDGES) {
        int e = edge_of[pos];
        int s = src_idx[e];
        int d = dst_idx[e];
        int2 v; v.x = s; v.y = d;
        sd[pos] = v;
        src_s[pos] = s;
        float td = edge_time[e] - node_time[d];
        float t0 = (td > 0.f) ? 1.f : ((td < 0.f) ? -1.f : 0.f);
        float t1 = log1pf(fabsf(td) * (1.f / 3600.f));
        tf[pos] = make_float2(t0, t1);
    }
}

// ---------- weight transpose+cvt: Wt[1024 n][256 k] bf16 ----------
__global__ __launch_bounds__(256) void wtrans_kernel(
    const float* __restrict__ Wq, const float* __restrict__ Wk,
    const float* __restrict__ Wv, const float* __restrict__ Wo,
    unsigned short* __restrict__ Wt)
{
    __shared__ float t[64][65];
    int nb = blockIdx.x * 64;
    int kb = blockIdx.y * 64;
    int g = nb >> 8;
    const float* W = (g == 0) ? Wq : (g == 1) ? Wk : (g == 2) ? Wv : Wo;
    int n0 = nb & 255;
    int tx = threadIdx.x & 63;
    int ty = threadIdx.x >> 6;
#pragma unroll
    for (int i = 0; i < 16; i++) {
        int k = i * 4 + ty;
        t[tx][k] = W[(size_t)(kb + k) * 256 + n0 + tx];
    }
    __syncthreads();
#pragma unroll
    for (int i = 0; i < 16; i++) {
        int n = i * 4 + ty;
        Wt[(size_t)(nb + n) * 256 + kb + tx] = f2bf(t[n][tx]);
    }
}

// ---------- pack W into MFMA fragment order: [g][cb][nf][c2][lane][8] ----------
__global__ __launch_bounds__(256) void wpack_kernel(
    const unsigned short* __restrict__ Wt, unsigned short* __restrict__ Wpk)
{
    int gid = blockIdx.x * 256 + threadIdx.x;
    int lane = gid & 63;
    int fragidx = gid >> 6;
    int c2 = fragidx & 7;
    int nf = (fragidx >> 3) & 3;
    int cb = (fragidx >> 5) & 3;
    int g = fragidx >> 7;
    int l16 = lane & 15;
    int kg = lane >> 4;
    int n_col = g * 256 + cb * 64 + nf * 16 + l16;
    int k0 = c2 * 32 + kg * 8;
    ushort8 v = *(const ushort8*)(Wt + (size_t)n_col * 256 + k0);
    *(ushort8*)(Wpk + (size_t)gid * 8) = v;
}

// ---------- QKV GEMM via MFMA, 64-row tiles, packed-W ----------
// q,k written as f16 head-major; v as bf16 head-major.
__global__ __launch_bounds__(256) void gemm_qkv_mfma7(
    const float* __restrict__ A, int M,
    const unsigned short* __restrict__ Wpk,
    const float* __restrict__ b0, const float* __restrict__ b1, const float* __restrict__ b2,
    unsigned short* __restrict__ O0, unsigned short* __restrict__ O1, unsigned short* __restrict__ O2)
{
    __shared__ unsigned short As[64 * 256];
    int tid = threadIdx.x;
    int rowbase = blockIdx.x * 64;

    {
        int rsub = tid >> 6;
        int c4 = (tid & 63) * 4;
        int cchunk = (tid & 63) >> 1;
        int sub = (tid & 1);
#pragma unroll
        for (int it = 0; it < 16; it++) {
            int row = it * 4 + rsub;
            int grow = rowbase + row;
            float4 av = make_float4(0.f, 0.f, 0.f, 0.f);
            if (grow < M) av = *(const float4*)(A + (size_t)grow * 256 + c4);
            ushort4 o;
            o.x = f2bf(av.x); o.y = f2bf(av.y); o.z = f2bf(av.z); o.w = f2bf(av.w);
            unsigned byte = row * 512 + ((unsigned)(cchunk ^ (row & 7)) << 4) + sub * 8;
            *(ushort4*)((char*)As + byte) = o;
        }
    }
    __syncthreads();

    int lane = tid & 63;
    int wid = tid >> 6;
    int l16 = lane & 15;
    int kg = lane >> 4;

#pragma unroll
    for (int p = 0; p < 3; p++) {
        const float* bias = (p == 0) ? b0 : (p == 1) ? b1 : b2;
        unsigned short* O = (p == 0) ? O0 : (p == 1) ? O1 : O2;

        f32x4 acc[4][4];
#pragma unroll
        for (int m = 0; m < 4; m++)
#pragma unroll
            for (int n = 0; n < 4; n++) acc[m][n] = (f32x4)(0.0f);

        const ushort8* wbase = (const ushort8*)(Wpk + ((size_t)(p * 4 + wid) * 2048 + lane) * 8);

#pragma unroll
        for (int c2 = 0; c2 < 8; c2++) {
            bf16x8 wfr[4];
#pragma unroll
            for (int n = 0; n < 4; n++) {
                BF8 t; t.u = wbase[(n * 8 + c2) * 64];
                wfr[n] = t.b;
            }
            bf16x8 afr[4];
#pragma unroll
            for (int m = 0; m < 4; m++) {
                int row = m * 16 + l16;
                int cchunk = (c2 * 4 + kg) ^ (row & 7);
                BF8 t;
                t.u = *(const ushort8*)((const char*)As + row * 512 + (cchunk << 4));
                afr[m] = t.b;
            }
#pragma unroll
            for (int m = 0; m < 4; m++)
#pragma unroll
                for (int n = 0; n < 4; n++)
                    acc[m][n] = __builtin_amdgcn_mfma_f32_16x16x32_bf16(wfr[n], afr[m], acc[m][n], 0, 0, 0);
        }

#pragma unroll
        for (int m = 0; m < 4; m++) {
            int node = rowbase + m * 16 + l16;
            if (node >= M) continue;
#pragma unroll
            for (int n = 0; n < 4; n++) {
                int lc = wid * 64 + n * 16 + kg * 4;
                float4 bv = *(const float4*)(bias + lc);
                ushort4 o;
                if (p < 2) {      // q,k -> f16
                    o.x = f2h(acc[m][n][0] + bv.x);
                    o.y = f2h(acc[m][n][1] + bv.y);
                    o.z = f2h(acc[m][n][2] + bv.z);
                    o.w = f2h(acc[m][n][3] + bv.w);
                } else {          // v -> bf16
                    o.x = f2bf(acc[m][n][0] + bv.x);
                    o.y = f2bf(acc[m][n][1] + bv.y);
                    o.z = f2bf(acc[m][n][2] + bv.z);
                    o.w = f2bf(acc[m][n][3] + bv.w);
                }
                int hh = lc >> 5, dd = lc & 31;
                *(ushort4*)(O + ((size_t)hh * NUM_NODES + node) * 32 + dd) = o;
            }
        }
    }
}

// ---------- output GEMM, 64-row tiles, packed-W; per-head scale in staging ----------
__global__ __launch_bounds__(256) void gemm_out_mfma6(
    const unsigned short* __restrict__ aggb, int M,
    const unsigned short* __restrict__ Wpk,
    const float* __restrict__ bias, const float* __restrict__ kscale,
    float* __restrict__ C)
{
    __shared__ unsigned short As[64 * 256];
    int tid = threadIdx.x;
    int rowbase = blockIdx.x * 64;

    {
        int rsub = tid >> 6;
        int c4 = (tid & 63) * 4;
        int cchunk = (tid & 63) >> 1;
        int sub = (tid & 1);
        int hh = c4 >> 5, dd = c4 & 31;
        float ks = kscale[hh];
#pragma unroll
        for (int it = 0; it < 16; it++) {
            int row = it * 4 + rsub;
            int grow = rowbase + row;
            ushort4 av = make_ushort4(0, 0, 0, 0);
            if (grow < M) av = *(const ushort4*)(aggb + ((size_t)hh * NUM_NODES + grow) * 32 + dd);
            ushort4 o;
            o.x = f2bf(bf2f(av.x) * ks); o.y = f2bf(bf2f(av.y) * ks);
            o.z = f2bf(bf2f(av.z) * ks); o.w = f2bf(bf2f(av.w) * ks);
            unsigned byte = row * 512 + ((unsigned)(cchunk ^ (row & 7)) << 4) + sub * 8;
            *(ushort4*)((char*)As + byte) = o;
        }
    }
    __syncthreads();

    int lane = tid & 63;
    int wid = tid >> 6;
    int l16 = lane & 15;
    int kg = lane >> 4;

    f32x4 acc[4][4];
#pragma unroll
    for (int m = 0; m < 4; m++)
#pragma unroll
        for (int n = 0; n < 4; n++) acc[m][n] = (f32x4)(0.0f);

    const ushort8* wbase = (const ushort8*)(Wpk + ((size_t)wid * 2048 + lane) * 8);

#pragma unroll
    for (int c2 = 0; c2 < 8; c2++) {
        bf16x8 wfr[4];
#pragma unroll
        for (int n = 0; n < 4; n++) {
            BF8 t; t.u = wbase[(n * 8 + c2) * 64];
            wfr[n] = t.b;
        }
        bf16x8 afr[4];
#pragma unroll
        for (int m = 0; m < 4; m++) {
            int row = m * 16 + l16;
            int cchunk = (c2 * 4 + kg) ^ (row & 7);
            BF8 t;
            t.u = *(const ushort8*)((const char*)As + row * 512 + (cchunk << 4));
            afr[m] = t.b;
        }
#pragma unroll
        for (int m = 0; m < 4; m++)
#pragma unroll
            for (int n = 0; n < 4; n++)
                acc[m][n] = __builtin_amdgcn_mfma_f32_16x16x32_bf16(wfr[n], afr[m], acc[m][n], 0, 0, 0);
    }

#pragma unroll
    for (int m = 0; m < 4; m++) {
        int node = rowbase + m * 16 + l16;
        if (node >= M) continue;
#pragma unroll
        for (int n = 0; n < 4; n++) {
            int col = wid * 64 + n * 16 + kg * 4;
            float4 bv = *(const float4*)(bias + col);
            float4 o;
            o.x = acc[m][n][0] + bv.x;
            o.y = acc[m][n][1] + bv.y;
            o.z = acc[m][n][2] + bv.z;
            o.w = acc[m][n][3] + bv.w;
            *(float4*)(C + (size_t)node * 256 + col) = o;
        }
    }
}

// ---------- scores: f16 q/k, fdot2, precomputed tf; head-pinned; fp32 out ----------
__global__ __launch_bounds__(256) void score4_kernel(
    const unsigned short* __restrict__ qh, const unsigned short* __restrict__ kh,
    const int2* __restrict__ sd, const float2* __restrict__ tf,
    const float* __restrict__ Wt, const float* __restrict__ bt,
    float* __restrict__ scores, unsigned* __restrict__ partialmax)
{
    __shared__ unsigned sm;
    int tid = threadIdx.x;
    if (tid == 0) sm = 0u;
    __syncthreads();
    int h = blockIdx.x & 7;
    int blk = blockIdx.x >> 3;               // 0..255
    float wt0 = Wt[h], wt1 = Wt[8 + h], btv = bt[h];
    const unsigned short* qhh = qh + (size_t)h * NUM_NODES * 32;
    const unsigned short* khh = kh + (size_t)h * NUM_NODES * 32;
    float* sc_h = scores + (size_t)h * NUM_EDGES;
    unsigned mykey = 0u;
    const int stride = 256 * 256;
    for (int pos = blk * 256 + tid; pos < NUM_EDGES; pos += stride) {
        int2 e = sd[pos];
        float2 t = tf[pos];
        const ushort8* qp = (const ushort8*)(qhh + (size_t)e.y * 32);
        const ushort8* kp = (const ushort8*)(khh + (size_t)e.x * 32);
        float dotv = 0.f;
#pragma unroll
        for (int i = 0; i < 4; i++) {
            H8 a, b;
            a.u = qp[i]; b.u = kp[i];
#pragma unroll
            for (int j = 0; j < 4; j++) dotv = FDOT2(a.h[j], b.h[j], dotv);
        }
        float sc = dotv * 0.17677669529663687f + (t.x * wt0 + t.y * wt1 + btv);
        sc_h[pos] = sc;
        unsigned kkey = float_to_key(sc);
        mykey = (kkey > mykey) ? kkey : mykey;
    }
#pragma unroll
    for (int off = 32; off > 0; off >>= 1) {
        unsigned o = __shfl_xor(mykey, off, 64);
        mykey = (o > mykey) ? o : mykey;
    }
    if ((tid & 63) == 0) atomicMax(&sm, mykey);
    __syncthreads();
    if (tid == 0) partialmax[blockIdx.x] = sm;
}

// partialmax[2048], entry i belongs to head i&7 (256 per head)
__global__ __launch_bounds__(256) void reduce_max3_kernel(
    const unsigned* __restrict__ partialmax, float* __restrict__ headmax)
{
    int tid = threadIdx.x;
    int h = tid >> 5, lane = tid & 31;
    unsigned m = 0u;
    for (int i = lane; i < 256; i += 32) {
        unsigned v = partialmax[i * 8 + h];
        m = (v > m) ? v : m;
    }
    for (int off = 16; off > 0; off >>= 1) {
        unsigned o = __shfl_down(m, off, 32);
        m = (o > m) ? o : m;
    }
    if (lane == 0) headmax[h] = key_to_float(m);
}

// ---------- aggregate7: head-pinned, LDS-staged src + inline exp, psum partials ----------
__global__ __launch_bounds__(256) void aggregate7_kernel(
    const unsigned short* __restrict__ vh, const float* __restrict__ scores,
    const int* __restrict__ src_s, const int* __restrict__ offs,
    const float* __restrict__ headmax, unsigned short* __restrict__ aggb,
    float* __restrict__ psum_part)
{
    __shared__ int sSrc[512];
    __shared__ float sP[512];
    __shared__ float blocksum;
    int tid = threadIdx.x;
    int h = blockIdx.x & 7;
    int chunk = blockIdx.x >> 3;
    int nodebase = chunk * 32;
    int g = tid >> 3;
    int ln = tid & 7;
    int node = nodebase + g;
    float m = headmax[h];
    const float* sc_h = scores + (size_t)h * NUM_EDGES;
    const unsigned short* vhh = vh + (size_t)h * NUM_NODES * 32;
    if (tid == 0) blocksum = 0.f;

    int blkstart = offs[nodebase];
    int blkend = offs[(nodebase + 32 < NUM_NODES) ? (nodebase + 32) : NUM_NODES];
    int start = 0, end = 0;
    if (node < NUM_NODES) { start = offs[node]; end = offs[node + 1]; }

    f32x4 a0 = (f32x4)(0.f), a1 = (f32x4)(0.f);
    float ps = 0.f;

    for (int t0 = blkstart; t0 < blkend; t0 += 512) {
        int cnt = min(512, blkend - t0);
        __syncthreads();
        for (int i = tid; i < cnt; i += 256) {
            sSrc[i] = src_s[t0 + i];
            float p = __expf(sc_h[t0 + i] - m);
            sP[i] = p;
            ps += p;
        }
        __syncthreads();
        int lo = (start > t0) ? start : t0;
        int hi = (end < t0 + cnt) ? end : (t0 + cnt);
        int cb = lo;
        for (; cb + 2 <= hi; cb += 2) {
            int i0 = cb - t0;
            int s0 = sSrc[i0], s1 = sSrc[i0 + 1];
            float p0 = sP[i0], p1 = sP[i0 + 1];
            ushort4 v0 = *(const ushort4*)(vhh + (size_t)s0 * 32 + ln * 4);
            ushort4 v1 = *(const ushort4*)(vhh + (size_t)s1 * 32 + ln * 4);
            a0[0] += p0 * bf2f(v0.x); a0[1] += p0 * bf2f(v0.y);
            a0[2] += p0 * bf2f(v0.z); a0[3] += p0 * bf2f(v0.w);
            a1[0] += p1 * bf2f(v1.x); a1[1] += p1 * bf2f(v1.y);
            a1[2] += p1 * bf2f(v1.z); a1[3] += p1 * bf2f(v1.w);
        }
        if (cb < hi) {
            int i0 = cb - t0;
            int s0 = sSrc[i0];
            float p0 = sP[i0];
            ushort4 v0 = *(const ushort4*)(vhh + (size_t)s0 * 32 + ln * 4);
            a0[0] += p0 * bf2f(v0.x); a0[1] += p0 * bf2f(v0.y);
            a0[2] += p0 * bf2f(v0.z); a0[3] += p0 * bf2f(v0.w);
        }
    }

    if (node < NUM_NODES) {
        ushort4 o;
        o.x = f2bf(a0[0] + a1[0]); o.y = f2bf(a0[1] + a1[1]);
        o.z = f2bf(a0[2] + a1[2]); o.w = f2bf(a0[3] + a1[3]);
        *(ushort4*)(aggb + ((size_t)h * NUM_NODES + node) * 32 + ln * 4) = o;
    }

    __syncthreads();
#pragma unroll
    for (int off = 32; off > 0; off >>= 1) ps += __shfl_xor(ps, off, 64);
    if ((tid & 63) == 0) atomicAdd(&blocksum, ps);
    __syncthreads();
    if (tid == 0) psum_part[blockIdx.x] = blocksum;
}

__global__ __launch_bounds__(256) void reduce_psum2_kernel(
    const float* __restrict__ psum_part, float* __restrict__ headinv)
{
    int tid = threadIdx.x;
    int h = tid >> 5, lane = tid & 31;
    float s = 0.f;
    for (int i = lane; i < NCHUNK32; i += 32) s += psum_part[i * 8 + h];
    for (int off = 16; off > 0; off >>= 1) s += __shfl_down(s, off, 32);
    if (lane == 0) headinv[h] = 1.f / s;
}

extern "C" void kernel_launch(void* const* d_in, const int* in_sizes, int n_in,
                              void* d_out, int out_size, void* d_ws, size_t ws_size,
                              hipStream_t stream) {
    const float* x = (const float*)d_in[0];
    const int* ei = (const int*)d_in[1];
    const int* src_idx = ei;
    const int* dst_idx = ei + NUM_EDGES;
    const float* edge_time = (const float*)d_in[2];
    const float* node_time = (const float*)d_in[3];
    const float* Wq = (const float*)d_in[4];  const float* bq = (const float*)d_in[5];
    const float* Wk = (const float*)d_in[6];  const float* bk = (const float*)d_in[7];
    const float* Wv = (const float*)d_in[8];  const float* bv = (const float*)d_in[9];
    const float* Wt = (const float*)d_in[10]; const float* bt = (const float*)d_in[11];
    const float* Wo = (const float*)d_in[12]; const float* bo = (const float*)d_in[13];
    float* out = (float*)d_out;

    char* w = (char*)d_ws;
    unsigned short* qb = (unsigned short*)w; w += (size_t)NUM_NODES * 256 * 2;  // [8][N][32] f16
    unsigned short* kb = (unsigned short*)w; w += (size_t)NUM_NODES * 256 * 2;  // [8][N][32] f16
    unsigned short* vb = (unsigned short*)w; w += (size_t)NUM_NODES * 256 * 2;  // [8][N][32] bf16
    float* scores = (float*)w;      w += (size_t)NUM_EDGES * 8 * 4;             // [8][E] fp32
    unsigned short* aggb = (unsigned short*)w; w += (size_t)NUM_NODES * 256 * 2; // [8][N][32]
    int2* sd = (int2*)w;            w += (size_t)NUM_EDGES * 8;
    float2* tfb = (float2*)w;       w += (size_t)NUM_EDGES * 8;
    int* src_s = (int*)w;           w += (size_t)NUM_EDGES * 4;
    int* edge_of = (int*)w;         w += (size_t)NUM_EDGES * 4;
    int* deg = (int*)w;             w += (size_t)NUM_NODES * 4;
    int* offs = (int*)w;            w += (size_t)(NUM_NODES + 1) * 4;
    int* cursor = (int*)w;          w += (size_t)NUM_NODES * 4;
    unsigned* partialmax = (unsigned*)w; w += 2048 * 4;
    float* psum_part = (float*)w;   w += (size_t)NCHUNK32 * 8 * 4;
    float* headmax = (float*)w;     w += 8 * 4;
    float* headinv = (float*)w;     w += 8 * 4;
    int* blocksum = (int*)w;        w += 64 * 4;
    int* bcarry = (int*)w;          w += 64 * 4;
    unsigned short* Wtb = (unsigned short*)w; w += (size_t)1024 * 256 * 2;
    unsigned short* Wpk = (unsigned short*)w; w += (size_t)1024 * 256 * 2;

    hipMemsetAsync(deg, 0, (size_t)NUM_NODES * 4, stream);

    // weight transpose + bf16 cvt, then fragment-pack
    dim3 gw(16, 4);
    wtrans_kernel<<<gw, 256, 0, stream>>>(Wq, Wk, Wv, Wo, Wtb);
    wpack_kernel<<<128, 256, 0, stream>>>(Wtb, Wpk);

    // CSR by dst (parallel scan); minimal scatter then gather-fill
    deg_kernel<<<(NUM_EDGES + 255) / 256, 256, 0, stream>>>(dst_idx, deg);
    scanA_kernel<<<SCAN_BLOCKS, 1024, 0, stream>>>(deg, offs, blocksum);
    scanB_kernel<<<1, 64, 0, stream>>>(blocksum, bcarry, offs);
    scanC_kernel<<<(NUM_NODES + 255) / 256, 256, 0, stream>>>(offs, bcarry, cursor);
    fillA_kernel<<<(NUM_EDGES + 255) / 256, 256, 0, stream>>>(dst_idx, cursor, edge_of);
    fillB_kernel<<<(NUM_EDGES + 255) / 256, 256, 0, stream>>>(
        edge_of, src_idx, dst_idx, edge_time, node_time, sd, tfb, src_s);

    // QKV projection -> head-major q/k (f16) + v (bf16)
    gemm_qkv_mfma7<<<(NUM_NODES + 63) / 64, 256, 0, stream>>>(
        x, NUM_NODES, Wpk, bq, bk, bv, qb, kb, vb);

    // scores (head-pinned, fdot2) + per-head max
    score4_kernel<<<2048, 256, 0, stream>>>(qb, kb, sd, tfb, Wt, bt, scores, partialmax);
    reduce_max3_kernel<<<1, 256, 0, stream>>>(partialmax, headmax);

    // aggregate (head-pinned, LDS-staged src+p, inline exp) + psum partials
    aggregate7_kernel<<<NCHUNK32 * 8, 256, 0, stream>>>(
        vb, scores, src_s, offs, headmax, aggb, psum_part);
    reduce_psum2_kernel<<<1, 256, 0, stream>>>(psum_part, headinv);

    // output projection with per-head 1/sum folded into staging (packed-W)
    gemm_out_mfma6<<<(NUM_NODES + 63) / 64, 256, 0, stream>>>(
        aggb, NUM_NODES, Wpk + (size_t)768 * 256, bo, headinv, out);
}

// Round 20
// 339.429 us; speedup vs baseline: 1.1282x; 1.0641x over previous
//
#include <hip/hip_runtime.h>
#include <hip/hip_bf16.h>

#define NUM_NODES 50000
#define NUM_EDGES 800000
#define NUM_HEADS 8
#define HEAD_DIM 32
#define SCAN_BLOCKS 49
#define NCHUNK32 1563   // ceil(50000/32)

typedef unsigned short ushort8 __attribute__((ext_vector_type(8)));
typedef float f32x4 __attribute__((ext_vector_type(4)));
typedef __bf16 bf16x8 __attribute__((ext_vector_type(8)));
typedef _Float16 h2 __attribute__((ext_vector_type(2)));

union BF8 { ushort8 u; bf16x8 b; };
union H8 { ushort8 u; h2 h[4]; };

#if defined(__has_builtin)
#if __has_builtin(__builtin_amdgcn_fdot2)
#define FDOT2(a, b, c) __builtin_amdgcn_fdot2((a), (b), (c), false)
#endif
#endif
#ifndef FDOT2
#define FDOT2(a, b, c) ((float)(a)[0] * (float)(b)[0] + (float)(a)[1] * (float)(b)[1] + (c))
#endif

__device__ __forceinline__ float bf2f(unsigned short u) {
    return __uint_as_float(((unsigned)u) << 16);
}
__device__ __forceinline__ unsigned short f2bf(float f) {
    unsigned u = __float_as_uint(f);
    unsigned r = (u + 0x7fffu + ((u >> 16) & 1u)) >> 16;
    return (unsigned short)r;
}
__device__ __forceinline__ unsigned short f2h(float f) {
    _Float16 h = (_Float16)f;
    return *(unsigned short*)&h;
}
__device__ __forceinline__ float h2f(unsigned short u) {
    _Float16 h = *(const _Float16*)&u;
    return (float)h;
}

// ---------- CSR build ----------
__global__ __launch_bounds__(256) void deg_kernel(const int* __restrict__ dst_idx, int* __restrict__ deg) {
    int e = blockIdx.x * 256 + threadIdx.x;
    if (e < NUM_EDGES) atomicAdd(&deg[dst_idx[e]], 1);
}

__global__ __launch_bounds__(1024) void scanA_kernel(
    const int* __restrict__ deg, int* __restrict__ offs, int* __restrict__ blocksum)
{
    __shared__ int buf[1024];
    int tid = threadIdx.x;
    int i = blockIdx.x * 1024 + tid;
    int v = (i < NUM_NODES) ? deg[i] : 0;
    buf[tid] = v;
    __syncthreads();
    for (int off = 1; off < 1024; off <<= 1) {
        int t = (tid >= off) ? buf[tid - off] : 0;
        __syncthreads();
        buf[tid] += t;
        __syncthreads();
    }
    if (i < NUM_NODES) offs[i] = buf[tid] - v;
    if (tid == 1023) blocksum[blockIdx.x] = buf[1023];
}

__global__ __launch_bounds__(64) void scanB_kernel(
    const int* __restrict__ blocksum, int* __restrict__ carry, int* __restrict__ offs)
{
    if (threadIdx.x == 0) {
        int acc = 0;
        for (int b = 0; b < SCAN_BLOCKS; b++) { carry[b] = acc; acc += blocksum[b]; }
        offs[NUM_NODES] = acc;
    }
}

__global__ __launch_bounds__(256) void scanC_kernel(
    int* __restrict__ offs, const int* __restrict__ carry, int* __restrict__ cursor)
{
    int i = blockIdx.x * 256 + threadIdx.x;
    if (i < NUM_NODES) {
        int v = offs[i] + carry[i >> 10];
        offs[i] = v;
        cursor[i] = v;
    }
}

// scatter ONLY edge_of (4B)
__global__ __launch_bounds__(256) void fillA_kernel(
    const int* __restrict__ dst_idx, int* __restrict__ cursor, int* __restrict__ edge_of)
{
    int e = blockIdx.x * 256 + threadIdx.x;
    if (e < NUM_EDGES) {
        int pos = atomicAdd(&cursor[dst_idx[e]], 1);
        edge_of[pos] = e;
    }
}

// gather pass: edata = { s|(d<<16) } | { f16(t0)|f16(t1)<<16 }<<32 ; plus src-only array
__global__ __launch_bounds__(256) void fillB_kernel(
    const int* __restrict__ edge_of,
    const int* __restrict__ src_idx, const int* __restrict__ dst_idx,
    const float* __restrict__ edge_time, const float* __restrict__ node_time,
    unsigned long long* __restrict__ edata, int* __restrict__ src_s)
{
    int pos = blockIdx.x * 256 + threadIdx.x;
    if (pos < NUM_EDGES) {
        int e = edge_of[pos];
        int s = src_idx[e];
        int d = dst_idx[e];
        float td = edge_time[e] - node_time[d];
        float t0 = (td > 0.f) ? 1.f : ((td < 0.f) ? -1.f : 0.f);
        float t1 = log1pf(fabsf(td) * (1.f / 3600.f));
        unsigned lo = (unsigned)s | ((unsigned)d << 16);
        unsigned hi = (unsigned)f2h(t0) | ((unsigned)f2h(t1) << 16);
        edata[pos] = (unsigned long long)lo | ((unsigned long long)hi << 32);
        src_s[pos] = s;
    }
}

// ---------- weight transpose+cvt: Wt[1024 n][256 k] bf16 ----------
__global__ __launch_bounds__(256) void wtrans_kernel(
    const float* __restrict__ Wq, const float* __restrict__ Wk,
    const float* __restrict__ Wv, const float* __restrict__ Wo,
    unsigned short* __restrict__ Wt)
{
    __shared__ float t[64][65];
    int nb = blockIdx.x * 64;
    int kb = blockIdx.y * 64;
    int g = nb >> 8;
    const float* W = (g == 0) ? Wq : (g == 1) ? Wk : (g == 2) ? Wv : Wo;
    int n0 = nb & 255;
    int tx = threadIdx.x & 63;
    int ty = threadIdx.x >> 6;
#pragma unroll
    for (int i = 0; i < 16; i++) {
        int k = i * 4 + ty;
        t[tx][k] = W[(size_t)(kb + k) * 256 + n0 + tx];
    }
    __syncthreads();
#pragma unroll
    for (int i = 0; i < 16; i++) {
        int n = i * 4 + ty;
        Wt[(size_t)(nb + n) * 256 + kb + tx] = f2bf(t[n][tx]);
    }
}

// ---------- pack W into MFMA fragment order ----------
__global__ __launch_bounds__(256) void wpack_kernel(
    const unsigned short* __restrict__ Wt, unsigned short* __restrict__ Wpk)
{
    int gid = blockIdx.x * 256 + threadIdx.x;
    int lane = gid & 63;
    int fragidx = gid >> 6;
    int c2 = fragidx & 7;
    int nf = (fragidx >> 3) & 3;
    int cb = (fragidx >> 5) & 3;
    int g = fragidx >> 7;
    int l16 = lane & 15;
    int kg = lane >> 4;
    int n_col = g * 256 + cb * 64 + nf * 16 + l16;
    int k0 = c2 * 32 + kg * 8;
    ushort8 v = *(const ushort8*)(Wt + (size_t)n_col * 256 + k0);
    *(ushort8*)(Wpk + (size_t)gid * 8) = v;
}

// ---------- QKV GEMM via MFMA (q,k f16; v bf16; head-major) ----------
__global__ __launch_bounds__(256) void gemm_qkv_mfma7(
    const float* __restrict__ A, int M,
    const unsigned short* __restrict__ Wpk,
    const float* __restrict__ b0, const float* __restrict__ b1, const float* __restrict__ b2,
    unsigned short* __restrict__ O0, unsigned short* __restrict__ O1, unsigned short* __restrict__ O2)
{
    __shared__ unsigned short As[64 * 256];
    int tid = threadIdx.x;
    int rowbase = blockIdx.x * 64;

    {
        int rsub = tid >> 6;
        int c4 = (tid & 63) * 4;
        int cchunk = (tid & 63) >> 1;
        int sub = (tid & 1);
#pragma unroll
        for (int it = 0; it < 16; it++) {
            int row = it * 4 + rsub;
            int grow = rowbase + row;
            float4 av = make_float4(0.f, 0.f, 0.f, 0.f);
            if (grow < M) av = *(const float4*)(A + (size_t)grow * 256 + c4);
            ushort4 o;
            o.x = f2bf(av.x); o.y = f2bf(av.y); o.z = f2bf(av.z); o.w = f2bf(av.w);
            unsigned byte = row * 512 + ((unsigned)(cchunk ^ (row & 7)) << 4) + sub * 8;
            *(ushort4*)((char*)As + byte) = o;
        }
    }
    __syncthreads();

    int lane = tid & 63;
    int wid = tid >> 6;
    int l16 = lane & 15;
    int kg = lane >> 4;

#pragma unroll
    for (int p = 0; p < 3; p++) {
        const float* bias = (p == 0) ? b0 : (p == 1) ? b1 : b2;
        unsigned short* O = (p == 0) ? O0 : (p == 1) ? O1 : O2;

        f32x4 acc[4][4];
#pragma unroll
        for (int m = 0; m < 4; m++)
#pragma unroll
            for (int n = 0; n < 4; n++) acc[m][n] = (f32x4)(0.0f);

        const ushort8* wbase = (const ushort8*)(Wpk + ((size_t)(p * 4 + wid) * 2048 + lane) * 8);

#pragma unroll
        for (int c2 = 0; c2 < 8; c2++) {
            bf16x8 wfr[4];
#pragma unroll
            for (int n = 0; n < 4; n++) {
                BF8 t; t.u = wbase[(n * 8 + c2) * 64];
                wfr[n] = t.b;
            }
            bf16x8 afr[4];
#pragma unroll
            for (int m = 0; m < 4; m++) {
                int row = m * 16 + l16;
                int cchunk = (c2 * 4 + kg) ^ (row & 7);
                BF8 t;
                t.u = *(const ushort8*)((const char*)As + row * 512 + (cchunk << 4));
                afr[m] = t.b;
            }
#pragma unroll
            for (int m = 0; m < 4; m++)
#pragma unroll
                for (int n = 0; n < 4; n++)
                    acc[m][n] = __builtin_amdgcn_mfma_f32_16x16x32_bf16(wfr[n], afr[m], acc[m][n], 0, 0, 0);
        }

#pragma unroll
        for (int m = 0; m < 4; m++) {
            int node = rowbase + m * 16 + l16;
            if (node >= M) continue;
#pragma unroll
            for (int n = 0; n < 4; n++) {
                int lc = wid * 64 + n * 16 + kg * 4;
                float4 bv = *(const float4*)(bias + lc);
                ushort4 o;
                if (p < 2) {
                    o.x = f2h(acc[m][n][0] + bv.x);
                    o.y = f2h(acc[m][n][1] + bv.y);
                    o.z = f2h(acc[m][n][2] + bv.z);
                    o.w = f2h(acc[m][n][3] + bv.w);
                } else {
                    o.x = f2bf(acc[m][n][0] + bv.x);
                    o.y = f2bf(acc[m][n][1] + bv.y);
                    o.z = f2bf(acc[m][n][2] + bv.z);
                    o.w = f2bf(acc[m][n][3] + bv.w);
                }
                int hh = lc >> 5, dd = lc & 31;
                *(ushort4*)(O + ((size_t)hh * NUM_NODES + node) * 32 + dd) = o;
            }
        }
    }
}

// ---------- output GEMM, packed-W; per-head scale in staging ----------
__global__ __launch_bounds__(256) void gemm_out_mfma6(
    const unsigned short* __restrict__ aggb, int M,
    const unsigned short* __restrict__ Wpk,
    const float* __restrict__ bias, const float* __restrict__ kscale,
    float* __restrict__ C)
{
    __shared__ unsigned short As[64 * 256];
    int tid = threadIdx.x;
    int rowbase = blockIdx.x * 64;

    {
        int rsub = tid >> 6;
        int c4 = (tid & 63) * 4;
        int cchunk = (tid & 63) >> 1;
        int sub = (tid & 1);
        int hh = c4 >> 5, dd = c4 & 31;
        float ks = kscale[hh];
#pragma unroll
        for (int it = 0; it < 16; it++) {
            int row = it * 4 + rsub;
            int grow = rowbase + row;
            ushort4 av = make_ushort4(0, 0, 0, 0);
            if (grow < M) av = *(const ushort4*)(aggb + ((size_t)hh * NUM_NODES + grow) * 32 + dd);
            ushort4 o;
            o.x = f2bf(bf2f(av.x) * ks); o.y = f2bf(bf2f(av.y) * ks);
            o.z = f2bf(bf2f(av.z) * ks); o.w = f2bf(bf2f(av.w) * ks);
            unsigned byte = row * 512 + ((unsigned)(cchunk ^ (row & 7)) << 4) + sub * 8;
            *(ushort4*)((char*)As + byte) = o;
        }
    }
    __syncthreads();

    int lane = tid & 63;
    int wid = tid >> 6;
    int l16 = lane & 15;
    int kg = lane >> 4;

    f32x4 acc[4][4];
#pragma unroll
    for (int m = 0; m < 4; m++)
#pragma unroll
        for (int n = 0; n < 4; n++) acc[m][n] = (f32x4)(0.0f);

    const ushort8* wbase = (const ushort8*)(Wpk + ((size_t)wid * 2048 + lane) * 8);

#pragma unroll
    for (int c2 = 0; c2 < 8; c2++) {
        bf16x8 wfr[4];
#pragma unroll
        for (int n = 0; n < 4; n++) {
            BF8 t; t.u = wbase[(n * 8 + c2) * 64];
            wfr[n] = t.b;
        }
        bf16x8 afr[4];
#pragma unroll
        for (int m = 0; m < 4; m++) {
            int row = m * 16 + l16;
            int cchunk = (c2 * 4 + kg) ^ (row & 7);
            BF8 t;
            t.u = *(const ushort8*)((const char*)As + row * 512 + (cchunk << 4));
            afr[m] = t.b;
        }
#pragma unroll
        for (int m = 0; m < 4; m++)
#pragma unroll
            for (int n = 0; n < 4; n++)
                acc[m][n] = __builtin_amdgcn_mfma_f32_16x16x32_bf16(wfr[n], afr[m], acc[m][n], 0, 0, 0);
    }

#pragma unroll
    for (int m = 0; m < 4; m++) {
        int node = rowbase + m * 16 + l16;
        if (node >= M) continue;
#pragma unroll
        for (int n = 0; n < 4; n++) {
            int col = wid * 64 + n * 16 + kg * 4;
            float4 bv = *(const float4*)(bias + col);
            float4 o;
            o.x = acc[m][n][0] + bv.x;
            o.y = acc[m][n][1] + bv.y;
            o.z = acc[m][n][2] + bv.z;
            o.w = acc[m][n][3] + bv.w;
            *(float4*)(C + (size_t)node * 256 + col) = o;
        }
    }
}

// ---------- score8: chunk-local q in LDS, no-max exp, p out + psum partials ----------
// block = 32 dst nodes x 1 head (head-pinned, chunk edge range contiguous).
__global__ __launch_bounds__(256) void score8_kernel(
    const unsigned short* __restrict__ qh, const unsigned short* __restrict__ kh,
    const unsigned long long* __restrict__ edata, const int* __restrict__ offs,
    const float* __restrict__ Wt, const float* __restrict__ bt,
    float* __restrict__ pb, float* __restrict__ psum_part)
{
    __shared__ unsigned short qs[32 * 40];   // 32 rows, 80B stride (bank spread)
    __shared__ float blocksum;
    int tid = threadIdx.x;
    int h = blockIdx.x & 7;
    int chunk = blockIdx.x >> 3;
    int nodebase = chunk * 32;
    float wt0 = Wt[h], wt1 = Wt[8 + h], btv = bt[h];
    const unsigned short* qhh = qh + (size_t)h * NUM_NODES * 32;
    const unsigned short* khh = kh + (size_t)h * NUM_NODES * 32;
    float* p_h = pb + (size_t)h * NUM_EDGES;
    if (tid == 0) blocksum = 0.f;

    // stage the chunk's 32 q rows (f16) into LDS
    if (tid < 128) {
        int row = tid >> 2, slot = tid & 3;
        int node = nodebase + row;
        ushort8 qv = (ushort8)(0);
        if (node < NUM_NODES) qv = *(const ushort8*)(qhh + (size_t)node * 32 + slot * 8);
        *(ushort8*)(qs + row * 40 + slot * 8) = qv;
    }
    __syncthreads();

    int blkstart = offs[nodebase];
    int nb_hi = (nodebase + 32 < NUM_NODES) ? (nodebase + 32) : NUM_NODES;
    int blkend = offs[nb_hi];

    float ps = 0.f;
    for (int pos = blkstart + tid; pos < blkend; pos += 256) {
        unsigned long long ed = edata[pos];
        unsigned lo32 = (unsigned)ed;
        unsigned hi32 = (unsigned)(ed >> 32);
        int s = lo32 & 0xffffu;
        int dloc = (int)(lo32 >> 16) - nodebase;
        float tf0 = h2f((unsigned short)(hi32 & 0xffffu));
        float tf1 = h2f((unsigned short)(hi32 >> 16));
        const ushort8* kp = (const ushort8*)(khh + (size_t)s * 32);
        const ushort8* qp = (const ushort8*)(qs + dloc * 40);
        float dotv = 0.f;
#pragma unroll
        for (int u = 0; u < 4; u++) {
            H8 a, b;
            a.u = qp[u]; b.u = kp[u];
#pragma unroll
            for (int j = 0; j < 4; j++) dotv = FDOT2(a.h[j], b.h[j], dotv);
        }
        float sc = dotv * 0.17677669529663687f + (tf0 * wt0 + tf1 * wt1 + btv);
        sc = fminf(sc, 80.f);
        float p = __expf(sc);
        p_h[pos] = p;
        ps += p;
    }
#pragma unroll
    for (int off = 32; off > 0; off >>= 1) ps += __shfl_xor(ps, off, 64);
    if ((tid & 63) == 0) atomicAdd(&blocksum, ps);
    __syncthreads();
    if (tid == 0) psum_part[blockIdx.x] = blocksum;
}

// psum_part[NCHUNK32*8], entry i belongs to head i&7
__global__ __launch_bounds__(256) void reduce_psum2_kernel(
    const float* __restrict__ psum_part, float* __restrict__ headinv)
{
    int tid = threadIdx.x;
    int h = tid >> 5, lane = tid & 31;
    float s = 0.f;
    for (int i = lane; i < NCHUNK32; i += 32) s += psum_part[i * 8 + h];
    for (int off = 16; off > 0; off >>= 1) s += __shfl_down(s, off, 32);
    if (lane == 0) headinv[h] = 1.f / s;
}

// ---------- aggregate8: staged p+src, 4-lane x 16B v-loads, 2-edge parity ----------
__global__ __launch_bounds__(256) void aggregate8_kernel(
    const unsigned short* __restrict__ vh, const float* __restrict__ pb,
    const int* __restrict__ src_s, const int* __restrict__ offs,
    unsigned short* __restrict__ aggb)
{
    __shared__ int sSrc[512];
    __shared__ float sP[512];
    int tid = threadIdx.x;
    int h = blockIdx.x & 7;
    int chunk = blockIdx.x >> 3;
    int nodebase = chunk * 32;
    int gg = tid >> 3;          // node within chunk
    int j = (tid >> 2) & 1;     // edge parity
    int ln4 = tid & 3;          // 16B slot (8 dims)
    int node = nodebase + gg;
    const float* p_h = pb + (size_t)h * NUM_EDGES;
    const unsigned short* vhh = vh + (size_t)h * NUM_NODES * 32;

    int blkstart = offs[nodebase];
    int nb_hi = (nodebase + 32 < NUM_NODES) ? (nodebase + 32) : NUM_NODES;
    int blkend = offs[nb_hi];
    int start = 0, end = 0;
    if (node < NUM_NODES) { start = offs[node]; end = offs[node + 1]; }

    f32x4 a0 = (f32x4)(0.f), a1 = (f32x4)(0.f);

    for (int t0 = blkstart; t0 < blkend; t0 += 512) {
        int cnt = min(512, blkend - t0);
        __syncthreads();
        for (int i = tid; i < cnt; i += 256) {
            sSrc[i] = src_s[t0 + i];
            sP[i] = p_h[t0 + i];
        }
        __syncthreads();
        int lo = (start > t0) ? start : t0;
        int hi = (end < t0 + cnt) ? end : (t0 + cnt);
        for (int cb = lo + j; cb < hi; cb += 2) {
            int i0 = cb - t0;
            int s0 = sSrc[i0];
            float p0 = sP[i0];
            ushort8 v = *(const ushort8*)(vhh + (size_t)s0 * 32 + ln4 * 8);
            a0[0] += p0 * bf2f(v[0]); a0[1] += p0 * bf2f(v[1]);
            a0[2] += p0 * bf2f(v[2]); a0[3] += p0 * bf2f(v[3]);
            a1[0] += p0 * bf2f(v[4]); a1[1] += p0 * bf2f(v[5]);
            a1[2] += p0 * bf2f(v[6]); a1[3] += p0 * bf2f(v[7]);
        }
    }

#pragma unroll
    for (int i = 0; i < 4; i++) {
        a0[i] += __shfl_xor(a0[i], 4, 64);
        a1[i] += __shfl_xor(a1[i], 4, 64);
    }
    if (node < NUM_NODES && j == 0) {
        ushort8 o;
        o[0] = f2bf(a0[0]); o[1] = f2bf(a0[1]); o[2] = f2bf(a0[2]); o[3] = f2bf(a0[3]);
        o[4] = f2bf(a1[0]); o[5] = f2bf(a1[1]); o[6] = f2bf(a1[2]); o[7] = f2bf(a1[3]);
        *(ushort8*)(aggb + ((size_t)h * NUM_NODES + node) * 32 + ln4 * 8) = o;
    }
}

extern "C" void kernel_launch(void* const* d_in, const int* in_sizes, int n_in,
                              void* d_out, int out_size, void* d_ws, size_t ws_size,
                              hipStream_t stream) {
    const float* x = (const float*)d_in[0];
    const int* ei = (const int*)d_in[1];
    const int* src_idx = ei;
    const int* dst_idx = ei + NUM_EDGES;
    const float* edge_time = (const float*)d_in[2];
    const float* node_time = (const float*)d_in[3];
    const float* Wq = (const float*)d_in[4];  const float* bq = (const float*)d_in[5];
    const float* Wk = (const float*)d_in[6];  const float* bk = (const float*)d_in[7];
    const float* Wv = (const float*)d_in[8];  const float* bv = (const float*)d_in[9];
    const float* Wt = (const float*)d_in[10]; const float* bt = (const float*)d_in[11];
    const float* Wo = (const float*)d_in[12]; const float* bo = (const float*)d_in[13];
    float* out = (float*)d_out;

    char* w = (char*)d_ws;
    unsigned short* qb = (unsigned short*)w; w += (size_t)NUM_NODES * 256 * 2;  // [8][N][32] f16
    unsigned short* kb = (unsigned short*)w; w += (size_t)NUM_NODES * 256 * 2;  // [8][N][32] f16
    unsigned short* vb = (unsigned short*)w; w += (size_t)NUM_NODES * 256 * 2;  // [8][N][32] bf16
    float* pb = (float*)w;          w += (size_t)NUM_EDGES * 8 * 4;             // [8][E] fp32
    unsigned short* aggb = (unsigned short*)w; w += (size_t)NUM_NODES * 256 * 2; // [8][N][32]
    unsigned long long* edata = (unsigned long long*)w; w += (size_t)NUM_EDGES * 8;
    int* src_s = (int*)w;           w += (size_t)NUM_EDGES * 4;
    int* edge_of = (int*)w;         w += (size_t)NUM_EDGES * 4;
    int* deg = (int*)w;             w += (size_t)NUM_NODES * 4;
    int* offs = (int*)w;            w += (size_t)(NUM_NODES + 1) * 4;
    int* cursor = (int*)w;          w += (size_t)NUM_NODES * 4;
    float* psum_part = (float*)w;   w += (size_t)NCHUNK32 * 8 * 4;
    float* headinv = (float*)w;     w += 8 * 4;
    int* blocksum = (int*)w;        w += 64 * 4;
    int* bcarry = (int*)w;          w += 64 * 4;
    unsigned short* Wtb = (unsigned short*)w; w += (size_t)1024 * 256 * 2;
    unsigned short* Wpk = (unsigned short*)w; w += (size_t)1024 * 256 * 2;

    hipMemsetAsync(deg, 0, (size_t)NUM_NODES * 4, stream);

    // weight transpose + bf16 cvt, then fragment-pack
    dim3 gw(16, 4);
    wtrans_kernel<<<gw, 256, 0, stream>>>(Wq, Wk, Wv, Wo, Wtb);
    wpack_kernel<<<128, 256, 0, stream>>>(Wtb, Wpk);

    // CSR by dst (parallel scan); minimal scatter then gather-fill
    deg_kernel<<<(NUM_EDGES + 255) / 256, 256, 0, stream>>>(dst_idx, deg);
    scanA_kernel<<<SCAN_BLOCKS, 1024, 0, stream>>>(deg, offs, blocksum);
    scanB_kernel<<<1, 64, 0, stream>>>(blocksum, bcarry, offs);
    scanC_kernel<<<(NUM_NODES + 255) / 256, 256, 0, stream>>>(offs, bcarry, cursor);
    fillA_kernel<<<(NUM_EDGES + 255) / 256, 256, 0, stream>>>(dst_idx, cursor, edge_of);
    fillB_kernel<<<(NUM_EDGES + 255) / 256, 256, 0, stream>>>(
        edge_of, src_idx, dst_idx, edge_time, node_time, edata, src_s);

    // QKV projection -> head-major q/k (f16) + v (bf16)
    gemm_qkv_mfma7<<<(NUM_NODES + 63) / 64, 256, 0, stream>>>(
        x, NUM_NODES, Wpk, bq, bk, bv, qb, kb, vb);

    // scores: chunk-local q in LDS, no-max exp, p + psum partials
    score8_kernel<<<NCHUNK32 * 8, 256, 0, stream>>>(
        qb, kb, edata, offs, Wt, bt, pb, psum_part);
    reduce_psum2_kernel<<<1, 256, 0, stream>>>(psum_part, headinv);

    // aggregate: staged p+src, 16B v-gathers
    aggregate8_kernel<<<NCHUNK32 * 8, 256, 0, stream>>>(
        vb, pb, src_s, offs, aggb);

    // output projection with per-head 1/sum folded into staging (packed-W)
    gemm_out_mfma6<<<(NUM_NODES + 63) / 64, 256, 0, stream>>>(
        aggb, NUM_NODES, Wpk + (size_t)768 * 256, bo, headinv, out);
}